// Round 3
// baseline (528.362 us; speedup 1.0000x reference)
//
#include <hip/hip_runtime.h>
#include <hip/hip_bf16.h>
#include <math.h>

typedef __hip_bfloat16 bf16;

#define R_TOT 4096   // B*N
#define NJ 31

// ---- workspace layout (float element offsets) ----
#define OFF_AE   0
#define OFF_Q    1048576
#define OFF_S1   2097152
#define OFF_SE   3145728
#define OFF_HW   4415488
#define OFF_ENT  4542464
#define OFF_X    4546560
#define OFF_W    5595136   // canonical fp32 weights base
// relative to W:
#define W_E1W   0
#define W_E1B   640
#define W_E2W   768
#define W_E2B   33536
#define W_H1W   33792
#define W_H1B   101120
#define W_H2WT  101376
#define W_H2B   166912
#define W_HEW   167168
#define W_HEB   167680
#define W_QW    167684
#define W_KW    233220
#define W_VW    235780
#define W_VB    238340
#define W_DECWT 238596
#define W_DECB  500740
#define W_TOTAL 501252
#define OFF_FLAG 6100992   // int flag

// ---- output element offsets ----
#define OUT0 0
#define OUT1 2097152
#define OUT2 2224128
#define OUT3 2351104
#define OUT4 2351105
#define OUT5 2478081

__device__ __forceinline__ float b2f(bf16 x) { return __bfloat162float(x); }
__device__ __forceinline__ float ldin(const void* p, int i, int flag) {
    return flag ? b2f(((const bf16*)p)[i]) : ((const float*)p)[i];
}
__device__ __forceinline__ void stout(void* p, int i, float v, int flag) {
    if (flag) ((bf16*)p)[i] = __float2bfloat16(v);
    else      ((float*)p)[i] = v;
}

// ---------------- K0: dtype detector ----------------
__global__ void k_detect(const void* emb, int* flagp) {
    int ln = threadIdx.x;
    float x = ((const float*)emb)[ln];   // 256 bytes; safe under either dtype
    int sane = (x == x) && (fabsf(x) < 1e20f);
    unsigned long long m = __ballot(sane);
    if (ln == 0) flagp[0] = (__popcll(m) == 64) ? 0 : 1;  // 0=fp32, 1=bf16
}

// ---------------- K0b: convert all weights to canonical fp32 (+transposes) ----------------
__global__ __launch_bounds__(256) void k_conv(
        const void* e1w, const void* e1b, const void* e2w, const void* e2b,
        const void* h1w, const void* h1b, const void* h2w, const void* h2b,
        const void* hew, const void* heb, const void* qw,  const void* kw,
        const void* vw,  const void* vb,  const void* decw,const void* decb,
        float* W, const int* flagp) {
    int flag = flagp[0];
    int idx = blockIdx.x * 256 + threadIdx.x;
    if (idx < 65536) {           // h2wT[c][d] = hm2_w[d][c]
        int c = idx >> 8, d = idx & 255;
        W[W_H2WT + c * 256 + d] = ldin(h2w, d * 256 + c, flag);
    }
    if (idx < 262144) {          // decT[c][o] = dec_w[o][c]
        int c = idx >> 9, o = idx & 511;
        W[W_DECWT + c * 512 + o] = ldin(decw, o * 512 + c, flag);
    }
    int j = idx - 262144;
    if (j >= 0 && j < 173570) {
        if      (j < 640)    W[W_E1W  + j]            = ldin(e1w,  j,          flag);
        else if (j < 768)    W[W_E1B  + (j - 640)]    = ldin(e1b,  j - 640,    flag);
        else if (j < 33536)  W[W_E2W  + (j - 768)]    = ldin(e2w,  j - 768,    flag);
        else if (j < 33792)  W[W_E2B  + (j - 33536)]  = ldin(e2b,  j - 33536,  flag);
        else if (j < 101120) W[W_H1W  + (j - 33792)]  = ldin(h1w,  j - 33792,  flag);
        else if (j < 101376) W[W_H1B  + (j - 101120)] = ldin(h1b,  j - 101120, flag);
        else if (j < 101632) W[W_H2B  + (j - 101376)] = ldin(h2b,  j - 101376, flag);
        else if (j < 102144) W[W_HEW  + (j - 101632)] = ldin(hew,  j - 101632, flag);
        else if (j < 102146) W[W_HEB  + (j - 102144)] = ldin(heb,  j - 102144, flag);
        else if (j < 167682) W[W_QW   + (j - 102146)] = ldin(qw,   j - 102146, flag);
        else if (j < 170242) W[W_KW   + (j - 167682)] = ldin(kw,   j - 167682, flag);
        else if (j < 172802) W[W_VW   + (j - 170242)] = ldin(vw,   j - 170242, flag);
        else if (j < 173058) W[W_VB   + (j - 172802)] = ldin(vb,   j - 172802, flag);
        else                 W[W_DECB + (j - 173058)] = ldin(decb, j - 173058, flag);
    }
}

// ---------------- K1: embed -> h -> agent_embed; q; s1 ----------------
__global__ __launch_bounds__(256) void k_embed(const void* emb, const float* W, const int* flagp,
                                               float* aews, float* qws, float* s1ws) {
    int flag = flagp[0];
    int r0 = blockIdx.x * 8;
    __shared__ float embL[8][12];
    __shared__ float hL[8][128];
    __shared__ float aeL[8][260];
    int tid = threadIdx.x;
    for (int idx = tid; idx < 8 * 11; idx += 256) {
        int s = idx / 11, t = idx % 11;
        embL[s][t] = ldin(emb, (r0 + s) * 11 + t, flag);
    }
    __syncthreads();
    for (int idx = tid; idx < 8 * 128; idx += 256) {
        int s = idx >> 7, j = idx & 127;
        float v = W[W_E1B + j];
#pragma unroll
        for (int t = 0; t < 5; t++) v += W[W_E1W + j * 5 + t] * embL[s][4 + t];
        hL[s][j] = v > 0.f ? v : 0.01f * v;
    }
    __syncthreads();
    {
        float acc[8];
#pragma unroll
        for (int s = 0; s < 8; s++) acc[s] = W[W_E2B + tid];
        for (int c = 0; c < 128; c++) {
            float w = W[W_E2W + tid * 128 + c];
#pragma unroll
            for (int s = 0; s < 8; s++) acc[s] += w * hL[s][c];
        }
#pragma unroll
        for (int s = 0; s < 8; s++) {
            float v = acc[s];
            v = v > 0.f ? v : 0.01f * v;
            aeL[s][tid] = v;
            aews[(r0 + s) * 256 + tid] = v;
        }
    }
    __syncthreads();
    {
        float acc[8];
#pragma unroll
        for (int s = 0; s < 8; s++) acc[s] = 0.f;
        for (int c = 0; c < 256; c++) {
            float w = W[W_QW + tid * 256 + c];
#pragma unroll
            for (int s = 0; s < 8; s++) acc[s] += w * aeL[s][c];
        }
#pragma unroll
        for (int s = 0; s < 8; s++) qws[(r0 + s) * 256 + tid] = acc[s];
    }
    {
        float acc[8];
#pragma unroll
        for (int s = 0; s < 8; s++) acc[s] = W[W_H1B + tid];
        for (int c = 0; c < 256; c++) {
            float w = W[W_H1W + tid * 263 + c];
#pragma unroll
            for (int s = 0; s < 8; s++) acc[s] += w * aeL[s][c];
        }
#pragma unroll
        for (int s = 0; s < 8; s++) s1ws[(r0 + s) * 256 + tid] = acc[s];
    }
}

// ---------------- K2: edge features (7) + goal polar (3) ----------------
__global__ void k_edges(const void* emb, const int* flagp, float* sews, void* out) {
    int flag = flagp[0];
    int idx = blockIdx.x * 256 + threadIdx.x;
    if (idx >= R_TOT * NJ) return;
    int r = idx / NJ, jp = idx - r * NJ;
    int b = r >> 5, i = r & 31;
    int j = jp + (jp >= i ? 1 : 0);
    int ei = r * 11, ej = (b * 32 + j) * 11;
    float pix = ldin(emb, ei + 0, flag), piy = ldin(emb, ei + 1, flag);
    float hix = ldin(emb, ei + 2, flag), hiy = ldin(emb, ei + 3, flag);
    float pjx = ldin(emb, ej + 0, flag), pjy = ldin(emb, ej + 1, flag);
    float hjx = ldin(emb, ej + 2, flag), hjy = ldin(emb, ej + 3, flag);
    float ajx = ldin(emb, ej + 7, flag), ajy = ldin(emb, ej + 8, flag);
    float gjx = ldin(emb, ej + 9, flag), gjy = ldin(emb, ej + 10, flag);
    float dx = pjx - pix, dy = pjy - piy;
    float dist = sqrtf(dx * dx + dy * dy);
    float hai = atan2f(hiy, hix);
    float ang = atan2f(dy, dx) - hai;
    float gx = gjx - pix, gy = gjy - piy;
    float gdist = sqrtf(gx * gx + gy * gy);
    float gang = atan2f(gy, gx) - hai;
    float* o = sews + idx * 10;
    o[0] = dist * (1.f / 12.f);
    o[1] = cosf(ang); o[2] = sinf(ang);
    o[3] = hjx; o[4] = hjy; o[5] = ajx; o[6] = ajy;
    o[7] = gdist; o[8] = cosf(gang); o[9] = sinf(gang);
    stout(out, OUT2 + idx, dist, flag);
}

// ---------------- K3: hard MLP + gumbel ----------------
__global__ __launch_bounds__(256) void k_hard(const float* s1ws, const float* sews, const float* W,
                                              const void* gum, const int* flagp,
                                              float* hwws, void* out) {
    int flag = flagp[0];
    int r = blockIdx.x;
    __shared__ float a1[32][256];
    __shared__ float edg[32][8];
    __shared__ float s1l[256];
    int tid = threadIdx.x;
    s1l[tid] = s1ws[r * 256 + tid];
    {
        int j = tid >> 3, t = tid & 7;
        float v = 0.f;
        if (j < NJ && t < 7) v = sews[(r * NJ + j) * 10 + t];
        edg[j][t] = v;
    }
    __syncthreads();
    float w1e[7];
#pragma unroll
    for (int t = 0; t < 7; t++) w1e[t] = W[W_H1W + tid * 263 + 256 + t];
    float s1c = s1l[tid];
    for (int j = 0; j < 32; j++) {
        float v = s1c;
#pragma unroll
        for (int t = 0; t < 7; t++) v += w1e[t] * edg[j][t];
        a1[j][tid] = fmaxf(v, 0.f);
    }
    __syncthreads();
    int wv = tid >> 6, ln = tid & 63;
    float acc[8][4];
#pragma unroll
    for (int jj = 0; jj < 8; jj++)
#pragma unroll
        for (int dd = 0; dd < 4; dd++) acc[jj][dd] = 0.f;

    const float* h2wT = W + W_H2WT;
    for (int c = 0; c < 256; c += 4) {
        float4 w4[4];
#pragma unroll
        for (int cc = 0; cc < 4; cc++)
            w4[cc] = *(const float4*)(h2wT + (c + cc) * 256 + 4 * ln);
#pragma unroll
        for (int jj = 0; jj < 8; jj++) {
            float4 a = *(const float4*)&a1[8 * wv + jj][c];
            float av[4] = {a.x, a.y, a.z, a.w};
#pragma unroll
            for (int cc = 0; cc < 4; cc++) {
                acc[jj][0] += ((const float*)&w4[cc])[0] * av[cc];
                acc[jj][1] += ((const float*)&w4[cc])[1] * av[cc];
                acc[jj][2] += ((const float*)&w4[cc])[2] * av[cc];
                acc[jj][3] += ((const float*)&w4[cc])[3] * av[cc];
            }
        }
    }
    float b2l[4], he0[4], he1[4];
#pragma unroll
    for (int dd = 0; dd < 4; dd++) {
        b2l[dd] = W[W_H2B + 4 * ln + dd];
        he0[dd] = W[W_HEW + 4 * ln + dd];
        he1[dd] = W[W_HEW + 256 + 4 * ln + dd];
    }
    float hb0 = W[W_HEB + 0], hb1 = W[W_HEB + 1];
#pragma unroll
    for (int jj = 0; jj < 8; jj++) {
        int jp = 8 * wv + jj;
        float p0 = 0.f, p1 = 0.f;
#pragma unroll
        for (int dd = 0; dd < 4; dd++) {
            float h2 = acc[jj][dd] + b2l[dd];
            p0 += he0[dd] * h2;
            p1 += he1[dd] * h2;
        }
#pragma unroll
        for (int s = 32; s >= 1; s >>= 1) {
            p0 += __shfl_xor(p0, s, 64);
            p1 += __shfl_xor(p1, s, 64);
        }
        if (ln == jj && jp < NJ) {
            float l0 = p0 + hb0, l1 = p1 + hb1;
            float u0 = ldin(gum, (r * NJ + jp) * 2 + 0, flag);
            float u1 = ldin(gum, (r * NJ + jp) * 2 + 1, flag);
            float g0 = -logf(-logf(u0 + 1e-10f) + 1e-10f);
            float g1 = -logf(-logf(u1 + 1e-10f) + 1e-10f);
            float dl = ((l1 + g1) - (l0 + g0)) * 2.0f;  // / tau (=0.5)
            float hwv = 1.f / (1.f + expf(-dl));
            stout(out, OUT1 + r * NJ + jp, l1, flag);
            stout(out, OUT4 + r * NJ + jp, hwv, flag);
            hwws[r * NJ + jp] = hwv;
        }
    }
}

// ---------------- K4: attention + softmax + combined + x + entropy + comb_w ----------------
__global__ __launch_bounds__(256) void k_attn(const float* qws, const float* sews, const float* hwws,
                                              const float* W, const int* flagp,
                                              float* xws, float* entws, void* out) {
    int flag = flagp[0];
    int r = blockIdx.x;
    __shared__ float qL[256];
    __shared__ float seL[NJ][10];
    __shared__ float KL[NJ][260];
    __shared__ float sL[32];
    __shared__ float cL[32];
    int tid = threadIdx.x;
    qL[tid] = qws[r * 256 + tid];
    for (int idx = tid; idx < NJ * 10; idx += 256) ((float*)seL)[idx] = sews[r * NJ * 10 + idx];
    __syncthreads();
    float kwr[10];
#pragma unroll
    for (int t = 0; t < 10; t++) kwr[t] = W[W_KW + tid * 10 + t];
    for (int j = 0; j < NJ; j++) {
        float v = 0.f;
#pragma unroll
        for (int t = 0; t < 10; t++) v += kwr[t] * seL[j][t];
        KL[j][tid] = v;
    }
    __syncthreads();
    int wv = tid >> 6, ln = tid & 63;
#pragma unroll
    for (int jj = 0; jj < 8; jj++) {
        int j = 8 * wv + jj;
        float p = 0.f;
        if (j < NJ) {
#pragma unroll
            for (int k2 = 0; k2 < 4; k2++) {
                int d = ln + 64 * k2;
                p += qL[d] * KL[j][d];
            }
        }
#pragma unroll
        for (int s = 32; s >= 1; s >>= 1) p += __shfl_xor(p, s, 64);
        if (j < NJ && ln == 0) sL[j] = p * (1.f / 16.f);
    }
    __syncthreads();
    if (wv == 0) {
        float sc = (ln < NJ) ? sL[ln] : -1e30f;
        float m = sc;
#pragma unroll
        for (int s = 32; s >= 1; s >>= 1) m = fmaxf(m, __shfl_xor(m, s, 64));
        float e = (ln < NJ) ? expf(sc - m) : 0.f;
        float sum = e;
#pragma unroll
        for (int s = 32; s >= 1; s >>= 1) sum += __shfl_xor(sum, s, 64);
        float sw = e / sum;
        float hv = (ln < NJ) ? hwws[r * NJ + ln] : 0.f;
        float cmb = sw * hv;
        if (ln < NJ) {
            cL[ln] = cmb;
            stout(out, OUT5 + r * NJ + ln, cmb, flag);
        }
        float csum = cmb;
#pragma unroll
        for (int s = 32; s >= 1; s >>= 1) csum += __shfl_xor(csum, s, 64);
        float cwn = cmb / (csum + 1e-6f);
        float et = (ln < NJ) ? -cwn * logf(cwn + 1e-6f) : 0.f;
#pragma unroll
        for (int s = 32; s >= 1; s >>= 1) et += __shfl_xor(et, s, 64);
        if (ln == 0) entws[r] = et;
    }
    __syncthreads();
    float vwr[10];
#pragma unroll
    for (int t = 0; t < 10; t++) vwr[t] = W[W_VW + tid * 10 + t];
    float vbv = W[W_VB + tid];
    float x = 0.f;
    for (int j = 0; j < NJ; j++) {
        float v = vbv;
#pragma unroll
        for (int t = 0; t < 10; t++) v += vwr[t] * seL[j][t];
        v = fmaxf(v, 0.f);
        x += v * cL[j];
    }
    xws[r * 256 + tid] = x;
}

// ---------------- K5: decoder ----------------
__global__ __launch_bounds__(256) void k_dec(const float* aews, const float* xws, const float* W,
                                             const int* flagp, void* out) {
    int flag = flagp[0];
    int r0 = blockIdx.x * 8;
    __shared__ float finL[8][516];
    int tid = threadIdx.x;
    for (int idx = tid; idx < 8 * 256; idx += 256) {
        int s = idx >> 8, c = idx & 255;
        finL[s][c] = aews[(r0 + s) * 256 + c];
        finL[s][256 + c] = xws[(r0 + s) * 256 + c];
    }
    __syncthreads();
    const float* decT = W + W_DECWT;
    float acc[8][2];
#pragma unroll
    for (int s = 0; s < 8; s++) { acc[s][0] = 0.f; acc[s][1] = 0.f; }
    for (int c = 0; c < 512; c++) {
        float2 w2 = *(const float2*)(decT + c * 512 + 2 * tid);
#pragma unroll
        for (int s = 0; s < 8; s++) {
            float f = finL[s][c];
            acc[s][0] += w2.x * f;
            acc[s][1] += w2.y * f;
        }
    }
    float b0 = W[W_DECB + 2 * tid], b1 = W[W_DECB + 2 * tid + 1];
#pragma unroll
    for (int s = 0; s < 8; s++) {
        stout(out, OUT0 + (r0 + s) * 512 + 2 * tid,     acc[s][0] + b0, flag);
        stout(out, OUT0 + (r0 + s) * 512 + 2 * tid + 1, acc[s][1] + b1, flag);
    }
}

// ---------------- K6: entropy mean ----------------
__global__ void k_ent(const float* entws, const int* flagp, void* out) {
    __shared__ float red[4];
    int tid = threadIdx.x;
    float s = 0.f;
    for (int i = tid; i < R_TOT; i += 256) s += entws[i];
#pragma unroll
    for (int m = 32; m >= 1; m >>= 1) s += __shfl_xor(s, m, 64);
    if ((tid & 63) == 0) red[tid >> 6] = s;
    __syncthreads();
    if (tid == 0) {
        float t = red[0] + red[1] + red[2] + red[3];
        stout(out, OUT3, t / (float)R_TOT, flagp[0]);
    }
}

// ---------------- launch ----------------
extern "C" void kernel_launch(void* const* d_in, const int* in_sizes, int n_in,
                              void* d_out, int out_size, void* d_ws, size_t ws_size,
                              hipStream_t stream) {
    const void* emb  = d_in[0];
    const void* gum  = d_in[1];
    const void* e1w  = d_in[2];
    const void* e1b  = d_in[3];
    const void* e2w  = d_in[4];
    const void* e2b  = d_in[5];
    const void* h1w  = d_in[6];
    const void* h1b  = d_in[7];
    const void* h2w  = d_in[8];
    const void* h2b  = d_in[9];
    const void* hew  = d_in[10];
    const void* heb  = d_in[11];
    const void* qw   = d_in[12];
    const void* kw   = d_in[13];
    const void* vw   = d_in[14];
    const void* vb   = d_in[15];
    const void* decw = d_in[16];
    const void* decb = d_in[17];

    float* wsf = (float*)d_ws;
    float* aews = wsf + OFF_AE;
    float* qws  = wsf + OFF_Q;
    float* s1ws = wsf + OFF_S1;
    float* sews = wsf + OFF_SE;
    float* hwws = wsf + OFF_HW;
    float* entw = wsf + OFF_ENT;
    float* xws  = wsf + OFF_X;
    float* W    = wsf + OFF_W;
    int* flagp  = (int*)(wsf + OFF_FLAG);

    hipLaunchKernelGGL(k_detect, dim3(1), dim3(64), 0, stream, emb, flagp);
    hipLaunchKernelGGL(k_conv, dim3(2048), dim3(256), 0, stream,
                       e1w, e1b, e2w, e2b, h1w, h1b, h2w, h2b, hew, heb,
                       qw, kw, vw, vb, decw, decb, W, flagp);
    hipLaunchKernelGGL(k_embed, dim3(512), dim3(256), 0, stream, emb, W, flagp, aews, qws, s1ws);
    hipLaunchKernelGGL(k_edges, dim3(496), dim3(256), 0, stream, emb, flagp, sews, d_out);
    hipLaunchKernelGGL(k_hard, dim3(4096), dim3(256), 0, stream,
                       s1ws, sews, W, gum, flagp, hwws, d_out);
    hipLaunchKernelGGL(k_attn, dim3(4096), dim3(256), 0, stream,
                       qws, sews, hwws, W, flagp, xws, entw, d_out);
    hipLaunchKernelGGL(k_dec, dim3(512), dim3(256), 0, stream, aews, xws, W, flagp, d_out);
    hipLaunchKernelGGL(k_ent, dim3(1), dim3(256), 0, stream, entw, flagp, d_out);
}

// Round 4
// 358.809 us; speedup vs baseline: 1.4725x; 1.4725x over previous
//
#include <hip/hip_runtime.h>
#include <hip/hip_bf16.h>
#include <math.h>

typedef __hip_bfloat16 bf16;
typedef short bf16x8 __attribute__((ext_vector_type(8)));
typedef float f32x4 __attribute__((ext_vector_type(4)));

#define R_TOT 4096   // B*N
#define NJ 31

// ---- workspace layout (float element offsets) ----
#define OFF_AE   0
#define OFF_Q    1048576
#define OFF_S1   2097152
#define OFF_SE   3145728
#define OFF_HW   4415488
#define OFF_ENT  4542464
#define OFF_X    4546560
#define OFF_W    5595136   // canonical fp32 weights base
// relative to W:
#define W_E1W   0
#define W_E1B   640
#define W_E2W   768
#define W_E2B   33536
#define W_H1W   33792
#define W_H1B   101120
#define W_H2WT  101376     // REUSED: Bpack (65536 bf16 = 128 KB) lives here now
#define W_H2B   166912
#define W_HEW   167168
#define W_HEB   167680
#define W_QW    167684
#define W_KW    233220
#define W_VW    235780
#define W_VB    238340
#define W_DECWT 238596
#define W_DECB  500740
#define OFF_FLAG 6100992   // int flag

// ---- output element offsets ----
#define OUT0 0
#define OUT1 2097152
#define OUT2 2224128
#define OUT3 2351104
#define OUT4 2351105
#define OUT5 2478081

__device__ __forceinline__ float b2f(bf16 x) { return __bfloat162float(x); }
__device__ __forceinline__ float ldin(const void* p, int i, int flag) {
    return flag ? b2f(((const bf16*)p)[i]) : ((const float*)p)[i];
}
__device__ __forceinline__ void stout(void* p, int i, float v, int flag) {
    if (flag) ((bf16*)p)[i] = __float2bfloat16(v);
    else      ((float*)p)[i] = v;
}
__device__ __forceinline__ unsigned short f2bbits(float v) {
    bf16 h = __float2bfloat16(v);
    return *(unsigned short*)&h;
}

// ---------------- K0: dtype detector ----------------
__global__ void k_detect(const void* emb, int* flagp) {
    int ln = threadIdx.x;
    float x = ((const float*)emb)[ln];   // 256 bytes; safe under either dtype
    int sane = (x == x) && (fabsf(x) < 1e20f);
    unsigned long long m = __ballot(sane);
    if (ln == 0) flagp[0] = (__popcll(m) == 64) ? 0 : 1;  // 0=fp32, 1=bf16
}

// ---------------- K0b: convert all weights to canonical fp32 (+transposes, +Bpack) ----------------
__global__ __launch_bounds__(256) void k_conv(
        const void* e1w, const void* e1b, const void* e2w, const void* e2b,
        const void* h1w, const void* h1b, const void* h2w, const void* h2b,
        const void* hew, const void* heb, const void* qw,  const void* kw,
        const void* vw,  const void* vb,  const void* decw,const void* decb,
        float* W, const int* flagp) {
    int flag = flagp[0];
    int idx = blockIdx.x * 256 + threadIdx.x;
    if (idx < 65536) {
        // Bpack: per-lane B-fragment order for mfma_f32_16x16x32_bf16
        // idx = ((kt*16 + nt)*64 + lane)*8 + j ; B[k][n] = hm2_w[n*256 + k]
        int jj   = idx & 7;
        int lane = (idx >> 3) & 63;
        int tile = idx >> 9;           // 0..127
        int nt = tile & 15, kt = tile >> 4;
        int n = nt * 16 + (lane & 15);
        int c = kt * 32 + ((lane >> 4) << 3) + jj;
        ((unsigned short*)(W + W_H2WT))[idx] = f2bbits(ldin(h2w, n * 256 + c, flag));
    }
    if (idx < 262144) {          // decT[c][o] = dec_w[o][c]
        int c = idx >> 9, o = idx & 511;
        W[W_DECWT + c * 512 + o] = ldin(decw, o * 512 + c, flag);
    }
    int j = idx - 262144;
    if (j >= 0 && j < 173570) {
        if      (j < 640)    W[W_E1W  + j]            = ldin(e1w,  j,          flag);
        else if (j < 768)    W[W_E1B  + (j - 640)]    = ldin(e1b,  j - 640,    flag);
        else if (j < 33536)  W[W_E2W  + (j - 768)]    = ldin(e2w,  j - 768,    flag);
        else if (j < 33792)  W[W_E2B  + (j - 33536)]  = ldin(e2b,  j - 33536,  flag);
        else if (j < 101120) W[W_H1W  + (j - 33792)]  = ldin(h1w,  j - 33792,  flag);
        else if (j < 101376) W[W_H1B  + (j - 101120)] = ldin(h1b,  j - 101120, flag);
        else if (j < 101632) W[W_H2B  + (j - 101376)] = ldin(h2b,  j - 101376, flag);
        else if (j < 102144) W[W_HEW  + (j - 101632)] = ldin(hew,  j - 101632, flag);
        else if (j < 102146) W[W_HEB  + (j - 102144)] = ldin(heb,  j - 102144, flag);
        else if (j < 167682) W[W_QW   + (j - 102146)] = ldin(qw,   j - 102146, flag);
        else if (j < 170242) W[W_KW   + (j - 167682)] = ldin(kw,   j - 167682, flag);
        else if (j < 172802) W[W_VW   + (j - 170242)] = ldin(vw,   j - 170242, flag);
        else if (j < 173058) W[W_VB   + (j - 172802)] = ldin(vb,   j - 172802, flag);
        else                 W[W_DECB + (j - 173058)] = ldin(decb, j - 173058, flag);
    }
}

// ---------------- K1: embed -> h -> agent_embed; q; s1 ----------------
__global__ __launch_bounds__(256) void k_embed(const void* emb, const float* W, const int* flagp,
                                               float* aews, float* qws, float* s1ws) {
    int flag = flagp[0];
    int r0 = blockIdx.x * 8;
    __shared__ float embL[8][12];
    __shared__ float hL[8][128];
    __shared__ float aeL[8][260];
    int tid = threadIdx.x;
    for (int idx = tid; idx < 8 * 11; idx += 256) {
        int s = idx / 11, t = idx % 11;
        embL[s][t] = ldin(emb, (r0 + s) * 11 + t, flag);
    }
    __syncthreads();
    for (int idx = tid; idx < 8 * 128; idx += 256) {
        int s = idx >> 7, j = idx & 127;
        float v = W[W_E1B + j];
#pragma unroll
        for (int t = 0; t < 5; t++) v += W[W_E1W + j * 5 + t] * embL[s][4 + t];
        hL[s][j] = v > 0.f ? v : 0.01f * v;
    }
    __syncthreads();
    {
        float acc[8];
#pragma unroll
        for (int s = 0; s < 8; s++) acc[s] = W[W_E2B + tid];
        for (int c = 0; c < 128; c++) {
            float w = W[W_E2W + tid * 128 + c];
#pragma unroll
            for (int s = 0; s < 8; s++) acc[s] += w * hL[s][c];
        }
#pragma unroll
        for (int s = 0; s < 8; s++) {
            float v = acc[s];
            v = v > 0.f ? v : 0.01f * v;
            aeL[s][tid] = v;
            aews[(r0 + s) * 256 + tid] = v;
        }
    }
    __syncthreads();
    {
        float acc[8];
#pragma unroll
        for (int s = 0; s < 8; s++) acc[s] = 0.f;
        for (int c = 0; c < 256; c++) {
            float w = W[W_QW + tid * 256 + c];
#pragma unroll
            for (int s = 0; s < 8; s++) acc[s] += w * aeL[s][c];
        }
#pragma unroll
        for (int s = 0; s < 8; s++) qws[(r0 + s) * 256 + tid] = acc[s];
    }
    {
        float acc[8];
#pragma unroll
        for (int s = 0; s < 8; s++) acc[s] = W[W_H1B + tid];
        for (int c = 0; c < 256; c++) {
            float w = W[W_H1W + tid * 263 + c];
#pragma unroll
            for (int s = 0; s < 8; s++) acc[s] += w * aeL[s][c];
        }
#pragma unroll
        for (int s = 0; s < 8; s++) s1ws[(r0 + s) * 256 + tid] = acc[s];
    }
}

// ---------------- K2: edge features (7) + goal polar (3) ----------------
__global__ void k_edges(const void* emb, const int* flagp, float* sews, void* out) {
    int flag = flagp[0];
    int idx = blockIdx.x * 256 + threadIdx.x;
    if (idx >= R_TOT * NJ) return;
    int r = idx / NJ, jp = idx - r * NJ;
    int b = r >> 5, i = r & 31;
    int j = jp + (jp >= i ? 1 : 0);
    int ei = r * 11, ej = (b * 32 + j) * 11;
    float pix = ldin(emb, ei + 0, flag), piy = ldin(emb, ei + 1, flag);
    float hix = ldin(emb, ei + 2, flag), hiy = ldin(emb, ei + 3, flag);
    float pjx = ldin(emb, ej + 0, flag), pjy = ldin(emb, ej + 1, flag);
    float hjx = ldin(emb, ej + 2, flag), hjy = ldin(emb, ej + 3, flag);
    float ajx = ldin(emb, ej + 7, flag), ajy = ldin(emb, ej + 8, flag);
    float gjx = ldin(emb, ej + 9, flag), gjy = ldin(emb, ej + 10, flag);
    float dx = pjx - pix, dy = pjy - piy;
    float dist = sqrtf(dx * dx + dy * dy);
    float hai = atan2f(hiy, hix);
    float ang = atan2f(dy, dx) - hai;
    float gx = gjx - pix, gy = gjy - piy;
    float gdist = sqrtf(gx * gx + gy * gy);
    float gang = atan2f(gy, gx) - hai;
    float* o = sews + idx * 10;
    o[0] = dist * (1.f / 12.f);
    o[1] = cosf(ang); o[2] = sinf(ang);
    o[3] = hjx; o[4] = hjy; o[5] = ajx; o[6] = ajy;
    o[7] = gdist; o[8] = cosf(gang); o[9] = sinf(gang);
    stout(out, OUT2 + idx, dist, flag);
}

// ---------------- K3: hard MLP via MFMA + gumbel ----------------
__global__ __launch_bounds__(256) void k_hard(const float* s1ws, const float* sews, const float* W,
                                              const void* gum, const int* flagp,
                                              float* hwws, void* out) {
    int flag = flagp[0];
    int r = blockIdx.x;
    __shared__ unsigned short a1[32][264];   // bf16, row padded +8 (16 B) -> 4-bank rotation
    __shared__ float edg[32][8];
    __shared__ float pj0[4][32];
    __shared__ float pj1[4][32];
    int tid = threadIdx.x;
    {
        int j = tid >> 3, t = tid & 7;
        float v = 0.f;
        if (j < NJ && t < 7) v = sews[(r * NJ + j) * 10 + t];
        edg[j][t] = v;
    }
    __syncthreads();
    // phase A: a1[j][c] = relu(s1[c] + W1e[c,:] . edge[j,:])  -> bf16 LDS
    float w1e[7];
#pragma unroll
    for (int t = 0; t < 7; t++) w1e[t] = W[W_H1W + tid * 263 + 256 + t];
    float s1c = s1ws[r * 256 + tid];
    for (int j = 0; j < 32; j++) {
        float v = s1c;
#pragma unroll
        for (int t = 0; t < 7; t++) v += w1e[t] * edg[j][t];
        a1[j][tid] = f2bbits(fmaxf(v, 0.f));
    }
    __syncthreads();
    // phase B: h2 = a1(32x256) @ B(256x256) via mfma 16x16x32
    int wv = tid >> 6, ln = tid & 63;
    int lr = ln & 15, quad = ln >> 4;
    const bf16x8* Bp = (const bf16x8*)(W + W_H2WT);   // [(kt*16+nt)*64 + lane] fragments
    f32x4 acc[2][4];
#pragma unroll
    for (int mt = 0; mt < 2; mt++)
#pragma unroll
        for (int nt = 0; nt < 4; nt++) acc[mt][nt] = (f32x4){0.f, 0.f, 0.f, 0.f};

#pragma unroll
    for (int kt = 0; kt < 8; kt++) {
        bf16x8 af[2];
#pragma unroll
        for (int mt = 0; mt < 2; mt++)
            af[mt] = *(const bf16x8*)&a1[mt * 16 + lr][kt * 32 + (quad << 3)];
#pragma unroll
        for (int nt = 0; nt < 4; nt++) {
            bf16x8 bf = Bp[(kt * 16 + (wv * 4 + nt)) * 64 + ln];
#pragma unroll
            for (int mt = 0; mt < 2; mt++)
                acc[mt][nt] = __builtin_amdgcn_mfma_f32_16x16x32_bf16(af[mt], bf, acc[mt][nt], 0, 0, 0);
        }
    }
    // epilogue: logits p0/p1 per j-row; fold hm2_b via he.b2 constant
    float he0v[4], he1v[4], b2v[4];
#pragma unroll
    for (int nt = 0; nt < 4; nt++) {
        int d = wv * 64 + nt * 16 + lr;
        he0v[nt] = W[W_HEW + d];
        he1v[nt] = W[W_HEW + 256 + d];
        b2v[nt]  = W[W_H2B + d];
    }
    float cb0 = 0.f, cb1 = 0.f;
#pragma unroll
    for (int nt = 0; nt < 4; nt++) { cb0 += he0v[nt] * b2v[nt]; cb1 += he1v[nt] * b2v[nt]; }
#pragma unroll
    for (int mt = 0; mt < 2; mt++) {
#pragma unroll
        for (int reg = 0; reg < 4; reg++) {
            float p0 = cb0, p1 = cb1;
#pragma unroll
            for (int nt = 0; nt < 4; nt++) {
                float v = acc[mt][nt][reg];
                p0 += he0v[nt] * v;
                p1 += he1v[nt] * v;
            }
            // reduce over the 16 lanes (bits 0..3) sharing this j-row
#pragma unroll
            for (int s = 1; s <= 8; s <<= 1) {
                p0 += __shfl_xor(p0, s, 64);
                p1 += __shfl_xor(p1, s, 64);
            }
            if (lr == 0) {
                int j = mt * 16 + quad * 4 + reg;
                pj0[wv][j] = p0;
                pj1[wv][j] = p1;
            }
        }
    }
    __syncthreads();
    if (tid < NJ) {
        int j = tid;
        float p0 = pj0[0][j] + pj0[1][j] + pj0[2][j] + pj0[3][j];
        float p1 = pj1[0][j] + pj1[1][j] + pj1[2][j] + pj1[3][j];
        float l0 = p0 + W[W_HEB + 0], l1 = p1 + W[W_HEB + 1];
        float u0 = ldin(gum, (r * NJ + j) * 2 + 0, flag);
        float u1 = ldin(gum, (r * NJ + j) * 2 + 1, flag);
        float g0 = -logf(-logf(u0 + 1e-10f) + 1e-10f);
        float g1 = -logf(-logf(u1 + 1e-10f) + 1e-10f);
        float dl = ((l1 + g1) - (l0 + g0)) * 2.0f;  // / tau (=0.5)
        float hwv = 1.f / (1.f + expf(-dl));
        stout(out, OUT1 + r * NJ + j, l1, flag);
        stout(out, OUT4 + r * NJ + j, hwv, flag);
        hwws[r * NJ + j] = hwv;
    }
}

// ---------------- K4: attention + softmax + combined + x + entropy + comb_w ----------------
__global__ __launch_bounds__(256) void k_attn(const float* qws, const float* sews, const float* hwws,
                                              const float* W, const int* flagp,
                                              float* xws, float* entws, void* out) {
    int flag = flagp[0];
    int r = blockIdx.x;
    __shared__ float qL[256];
    __shared__ float seL[NJ][10];
    __shared__ float KL[NJ][260];
    __shared__ float sL[32];
    __shared__ float cL[32];
    int tid = threadIdx.x;
    qL[tid] = qws[r * 256 + tid];
    for (int idx = tid; idx < NJ * 10; idx += 256) ((float*)seL)[idx] = sews[r * NJ * 10 + idx];
    __syncthreads();
    float kwr[10];
#pragma unroll
    for (int t = 0; t < 10; t++) kwr[t] = W[W_KW + tid * 10 + t];
    for (int j = 0; j < NJ; j++) {
        float v = 0.f;
#pragma unroll
        for (int t = 0; t < 10; t++) v += kwr[t] * seL[j][t];
        KL[j][tid] = v;
    }
    __syncthreads();
    int wv = tid >> 6, ln = tid & 63;
#pragma unroll
    for (int jj = 0; jj < 8; jj++) {
        int j = 8 * wv + jj;
        float p = 0.f;
        if (j < NJ) {
#pragma unroll
            for (int k2 = 0; k2 < 4; k2++) {
                int d = ln + 64 * k2;
                p += qL[d] * KL[j][d];
            }
        }
#pragma unroll
        for (int s = 32; s >= 1; s >>= 1) p += __shfl_xor(p, s, 64);
        if (j < NJ && ln == 0) sL[j] = p * (1.f / 16.f);
    }
    __syncthreads();
    if (wv == 0) {
        float sc = (ln < NJ) ? sL[ln] : -1e30f;
        float m = sc;
#pragma unroll
        for (int s = 32; s >= 1; s >>= 1) m = fmaxf(m, __shfl_xor(m, s, 64));
        float e = (ln < NJ) ? expf(sc - m) : 0.f;
        float sum = e;
#pragma unroll
        for (int s = 32; s >= 1; s >>= 1) sum += __shfl_xor(sum, s, 64);
        float sw = e / sum;
        float hv = (ln < NJ) ? hwws[r * NJ + ln] : 0.f;
        float cmb = sw * hv;
        if (ln < NJ) {
            cL[ln] = cmb;
            stout(out, OUT5 + r * NJ + ln, cmb, flag);
        }
        float csum = cmb;
#pragma unroll
        for (int s = 32; s >= 1; s >>= 1) csum += __shfl_xor(csum, s, 64);
        float cwn = cmb / (csum + 1e-6f);
        float et = (ln < NJ) ? -cwn * logf(cwn + 1e-6f) : 0.f;
#pragma unroll
        for (int s = 32; s >= 1; s >>= 1) et += __shfl_xor(et, s, 64);
        if (ln == 0) entws[r] = et;
    }
    __syncthreads();
    float vwr[10];
#pragma unroll
    for (int t = 0; t < 10; t++) vwr[t] = W[W_VW + tid * 10 + t];
    float vbv = W[W_VB + tid];
    float x = 0.f;
    for (int j = 0; j < NJ; j++) {
        float v = vbv;
#pragma unroll
        for (int t = 0; t < 10; t++) v += vwr[t] * seL[j][t];
        v = fmaxf(v, 0.f);
        x += v * cL[j];
    }
    xws[r * 256 + tid] = x;
}

// ---------------- K5: decoder ----------------
__global__ __launch_bounds__(256) void k_dec(const float* aews, const float* xws, const float* W,
                                             const int* flagp, void* out) {
    int flag = flagp[0];
    int r0 = blockIdx.x * 8;
    __shared__ float finL[8][516];
    int tid = threadIdx.x;
    for (int idx = tid; idx < 8 * 256; idx += 256) {
        int s = idx >> 8, c = idx & 255;
        finL[s][c] = aews[(r0 + s) * 256 + c];
        finL[s][256 + c] = xws[(r0 + s) * 256 + c];
    }
    __syncthreads();
    const float* decT = W + W_DECWT;
    float acc[8][2];
#pragma unroll
    for (int s = 0; s < 8; s++) { acc[s][0] = 0.f; acc[s][1] = 0.f; }
    for (int c = 0; c < 512; c++) {
        float2 w2 = *(const float2*)(decT + c * 512 + 2 * tid);
#pragma unroll
        for (int s = 0; s < 8; s++) {
            float f = finL[s][c];
            acc[s][0] += w2.x * f;
            acc[s][1] += w2.y * f;
        }
    }
    float b0 = W[W_DECB + 2 * tid], b1 = W[W_DECB + 2 * tid + 1];
#pragma unroll
    for (int s = 0; s < 8; s++) {
        stout(out, OUT0 + (r0 + s) * 512 + 2 * tid,     acc[s][0] + b0, flag);
        stout(out, OUT0 + (r0 + s) * 512 + 2 * tid + 1, acc[s][1] + b1, flag);
    }
}

// ---------------- K6: entropy mean ----------------
__global__ void k_ent(const float* entws, const int* flagp, void* out) {
    __shared__ float red[4];
    int tid = threadIdx.x;
    float s = 0.f;
    for (int i = tid; i < R_TOT; i += 256) s += entws[i];
#pragma unroll
    for (int m = 32; m >= 1; m >>= 1) s += __shfl_xor(s, m, 64);
    if ((tid & 63) == 0) red[tid >> 6] = s;
    __syncthreads();
    if (tid == 0) {
        float t = red[0] + red[1] + red[2] + red[3];
        stout(out, OUT3, t / (float)R_TOT, flagp[0]);
    }
}

// ---------------- launch ----------------
extern "C" void kernel_launch(void* const* d_in, const int* in_sizes, int n_in,
                              void* d_out, int out_size, void* d_ws, size_t ws_size,
                              hipStream_t stream) {
    const void* emb  = d_in[0];
    const void* gum  = d_in[1];
    const void* e1w  = d_in[2];
    const void* e1b  = d_in[3];
    const void* e2w  = d_in[4];
    const void* e2b  = d_in[5];
    const void* h1w  = d_in[6];
    const void* h1b  = d_in[7];
    const void* h2w  = d_in[8];
    const void* h2b  = d_in[9];
    const void* hew  = d_in[10];
    const void* heb  = d_in[11];
    const void* qw   = d_in[12];
    const void* kw   = d_in[13];
    const void* vw   = d_in[14];
    const void* vb   = d_in[15];
    const void* decw = d_in[16];
    const void* decb = d_in[17];

    float* wsf = (float*)d_ws;
    float* aews = wsf + OFF_AE;
    float* qws  = wsf + OFF_Q;
    float* s1ws = wsf + OFF_S1;
    float* sews = wsf + OFF_SE;
    float* hwws = wsf + OFF_HW;
    float* entw = wsf + OFF_ENT;
    float* xws  = wsf + OFF_X;
    float* W    = wsf + OFF_W;
    int* flagp  = (int*)(wsf + OFF_FLAG);

    hipLaunchKernelGGL(k_detect, dim3(1), dim3(64), 0, stream, emb, flagp);
    hipLaunchKernelGGL(k_conv, dim3(2048), dim3(256), 0, stream,
                       e1w, e1b, e2w, e2b, h1w, h1b, h2w, h2b, hew, heb,
                       qw, kw, vw, vb, decw, decb, W, flagp);
    hipLaunchKernelGGL(k_embed, dim3(512), dim3(256), 0, stream, emb, W, flagp, aews, qws, s1ws);
    hipLaunchKernelGGL(k_edges, dim3(496), dim3(256), 0, stream, emb, flagp, sews, d_out);
    hipLaunchKernelGGL(k_hard, dim3(4096), dim3(256), 0, stream,
                       s1ws, sews, W, gum, flagp, hwws, d_out);
    hipLaunchKernelGGL(k_attn, dim3(4096), dim3(256), 0, stream,
                       qws, sews, hwws, W, flagp, xws, entw, d_out);
    hipLaunchKernelGGL(k_dec, dim3(512), dim3(256), 0, stream, aews, xws, W, flagp, d_out);
    hipLaunchKernelGGL(k_ent, dim3(1), dim3(256), 0, stream, entw, flagp, d_out);
}

// Round 5
// 271.266 us; speedup vs baseline: 1.9478x; 1.3227x over previous
//
#include <hip/hip_runtime.h>
#include <hip/hip_bf16.h>
#include <math.h>

typedef __hip_bfloat16 bf16;
typedef short bf16x8 __attribute__((ext_vector_type(8)));
typedef float f32x4 __attribute__((ext_vector_type(4)));

#define R_TOT 4096   // B*N
#define NJ 31

// ---- workspace layout (float element offsets) ----
#define OFF_AE   0
#define OFF_Q    1048576
#define OFF_S1   2097152
#define OFF_SE   3145728
#define OFF_HW   4415488
#define OFF_ENT  4542464
#define OFF_X    4546560
#define OFF_W    5595136   // canonical fp32 weights base
// relative to W:
#define W_E1W   0
#define W_E1B   640
#define W_E2P   768        // e2 B-pack: 32768 bf16 (reuses old fp32 e2w slot)
#define W_E2B   33536
#define W_H1W   33792
#define W_H1B   101120
#define W_H2WT  101376     // h2 B-pack: 65536 bf16
#define W_H2B   166912
#define W_HEW   167168
#define W_HEB   167680
#define W_QP    167684     // q B-pack: 65536 bf16 (reuses old fp32 qw slot)
#define W_S1P   200452     // s1 B-pack: 65536 bf16 (second half of old qw slot)
#define W_KW    233220
#define W_VW    235780
#define W_VB    238340
#define W_DECWT 238596
#define W_DECB  500740
#define OFF_FLAG 6100992   // int flag

// ---- output element offsets ----
#define OUT0 0
#define OUT1 2097152
#define OUT2 2224128
#define OUT3 2351104
#define OUT4 2351105
#define OUT5 2478081

__device__ __forceinline__ float b2f(bf16 x) { return __bfloat162float(x); }
__device__ __forceinline__ float ldin(const void* p, int i, int flag) {
    return flag ? b2f(((const bf16*)p)[i]) : ((const float*)p)[i];
}
__device__ __forceinline__ void stout(void* p, int i, float v, int flag) {
    if (flag) ((bf16*)p)[i] = __float2bfloat16(v);
    else      ((float*)p)[i] = v;
}
__device__ __forceinline__ unsigned short f2bbits(float v) {
    bf16 h = __float2bfloat16(v);
    return *(unsigned short*)&h;
}

// ---------------- K0: dtype detector ----------------
__global__ void k_detect(const void* emb, int* flagp) {
    int ln = threadIdx.x;
    float x = ((const float*)emb)[ln];
    int sane = (x == x) && (fabsf(x) < 1e20f);
    unsigned long long m = __ballot(sane);
    if (ln == 0) flagp[0] = (__popcll(m) == 64) ? 0 : 1;  // 0=fp32, 1=bf16
}

// ---------------- K0b: convert weights: fp32 canon + MFMA B-packs + decT ----------------
__global__ __launch_bounds__(256) void k_conv(
        const void* e1w, const void* e1b, const void* e2w, const void* e2b,
        const void* h1w, const void* h1b, const void* h2w, const void* h2b,
        const void* hew, const void* heb, const void* qw,  const void* kw,
        const void* vw,  const void* vb,  const void* decw,const void* decb,
        float* W, const int* flagp) {
    int flag = flagp[0];
    int idx = blockIdx.x * 256 + threadIdx.x;
    if (idx < 65536) {
        // h2 B-pack: idx = ((kt*16+nt)*64+lane)*8+jj ; B[k][n] = hm2_w[n*256+k]
        int jj   = idx & 7;
        int lane = (idx >> 3) & 63;
        int tile = idx >> 9;
        int nt = tile & 15, kt = tile >> 4;
        int n = nt * 16 + (lane & 15);
        int c = kt * 32 + ((lane >> 4) << 3) + jj;
        ((unsigned short*)(W + W_H2WT))[idx] = f2bbits(ldin(h2w, n * 256 + c, flag));
    }
    if (idx < 262144) {          // decT[c][o] = dec_w[o][c]
        int c = idx >> 9, o = idx & 511;
        W[W_DECWT + c * 512 + o] = ldin(decw, o * 512 + c, flag);
    }
    int j = idx - 262144;
    if (j >= 0 && j < 163840) {  // MFMA B-packs for e2 / q / s1
        int p, kt_max;
        const void* src; int ldm, Wdst;
        if (j < 32768)      { p = j;          src = e2w; ldm = 128; Wdst = W_E2P; }
        else if (j < 98304) { p = j - 32768;  src = qw;  ldm = 256; Wdst = W_QP;  }
        else                { p = j - 98304;  src = h1w; ldm = 263; Wdst = W_S1P; }
        int jj   = p & 7;
        int lane = (p >> 3) & 63;
        int tile = p >> 9;
        int nt = tile & 15, kt = tile >> 4;
        int n = nt * 16 + (lane & 15);
        int k = kt * 32 + ((lane >> 4) << 3) + jj;
        ((unsigned short*)(W + Wdst))[p] = f2bbits(ldin(src, n * ldm + k, flag));
        (void)kt_max;
    } else if (j >= 163840 && j < 239618) {   // fp32 canon for the rest
        int q2 = j - 163840;
        if      (q2 < 640)   W[W_E1W  + q2]           = ldin(e1w,  q2,          flag);
        else if (q2 < 768)   W[W_E1B  + (q2 - 640)]   = ldin(e1b,  q2 - 640,    flag);
        else if (q2 < 1024)  W[W_E2B  + (q2 - 768)]   = ldin(e2b,  q2 - 768,    flag);
        else if (q2 < 68352) W[W_H1W  + (q2 - 1024)]  = ldin(h1w,  q2 - 1024,   flag);
        else if (q2 < 68608) W[W_H1B  + (q2 - 68352)] = ldin(h1b,  q2 - 68352,  flag);
        else if (q2 < 68864) W[W_H2B  + (q2 - 68608)] = ldin(h2b,  q2 - 68608,  flag);
        else if (q2 < 69376) W[W_HEW  + (q2 - 68864)] = ldin(hew,  q2 - 68864,  flag);
        else if (q2 < 69378) W[W_HEB  + (q2 - 69376)] = ldin(heb,  q2 - 69376,  flag);
        else if (q2 < 71938) W[W_KW   + (q2 - 69378)] = ldin(kw,   q2 - 69378,  flag);
        else if (q2 < 74498) W[W_VW   + (q2 - 71938)] = ldin(vw,   q2 - 71938,  flag);
        else if (q2 < 74754) W[W_VB   + (q2 - 74498)] = ldin(vb,   q2 - 74498,  flag);
        else                 W[W_DECB + (q2 - 74754)] = ldin(decb, q2 - 74754,  flag);
    }
}

// ---------------- K1: embed MLP + q + s1, all via MFMA ----------------
__global__ __launch_bounds__(256) void k_embed(const void* emb, const float* W, const int* flagp,
                                               float* aews, float* qws, float* s1ws) {
    int flag = flagp[0];
    int r0 = blockIdx.x * 32;   // 128 blocks
    __shared__ float embL[32][12];
    __shared__ unsigned short hB[32][136];    // bf16 h, +8 pad
    __shared__ unsigned short aeB[32][264];   // bf16 ae, +8 pad
    int tid = threadIdx.x;
    for (int idx = tid; idx < 32 * 11; idx += 256) {
        int s = idx / 11, t = idx % 11;
        embL[s][t] = ldin(emb, (r0 + s) * 11 + t, flag);
    }
    __syncthreads();
    // h = leaky(emb5 @ e1w.T + b)  -> bf16 LDS
    for (int idx = tid; idx < 32 * 128; idx += 256) {
        int s = idx >> 7, jo = idx & 127;
        float v = W[W_E1B + jo];
#pragma unroll
        for (int t = 0; t < 5; t++) v += W[W_E1W + jo * 5 + t] * embL[s][4 + t];
        hB[s][jo] = f2bbits(v > 0.f ? v : 0.01f * v);
    }
    __syncthreads();
    int wv = tid >> 6, ln = tid & 63;
    int lr = ln & 15, quad = ln >> 4;
    // ae = leaky(h @ e2w.T + b): M=32, N=256, K=128
    {
        const bf16x8* Bp = (const bf16x8*)(W + W_E2P);
        f32x4 acc[2][4];
#pragma unroll
        for (int mt = 0; mt < 2; mt++)
#pragma unroll
            for (int nt = 0; nt < 4; nt++) acc[mt][nt] = (f32x4){0.f, 0.f, 0.f, 0.f};
#pragma unroll
        for (int kt = 0; kt < 4; kt++) {
            bf16x8 af[2];
#pragma unroll
            for (int mt = 0; mt < 2; mt++)
                af[mt] = *(const bf16x8*)&hB[mt * 16 + lr][kt * 32 + (quad << 3)];
#pragma unroll
            for (int nt = 0; nt < 4; nt++) {
                bf16x8 bfr = Bp[(kt * 16 + (wv * 4 + nt)) * 64 + ln];
#pragma unroll
                for (int mt = 0; mt < 2; mt++)
                    acc[mt][nt] = __builtin_amdgcn_mfma_f32_16x16x32_bf16(af[mt], bfr, acc[mt][nt], 0, 0, 0);
            }
        }
#pragma unroll
        for (int nt = 0; nt < 4; nt++) {
            int d = wv * 64 + nt * 16 + lr;
            float bias = W[W_E2B + d];
#pragma unroll
            for (int mt = 0; mt < 2; mt++)
#pragma unroll
                for (int reg = 0; reg < 4; reg++) {
                    int m = mt * 16 + quad * 4 + reg;
                    float v = acc[mt][nt][reg] + bias;
                    v = v > 0.f ? v : 0.01f * v;
                    aeB[m][d] = f2bbits(v);
                    aews[(r0 + m) * 256 + d] = v;
                }
        }
    }
    __syncthreads();
    // q = ae @ qw.T ; s1 = ae @ h1w[:,:256].T + h1b : M=32, N=256, K=256
    {
        const bf16x8* Bq = (const bf16x8*)(W + W_QP);
        const bf16x8* Bs = (const bf16x8*)(W + W_S1P);
        f32x4 qac[2][4], sac[2][4];
#pragma unroll
        for (int mt = 0; mt < 2; mt++)
#pragma unroll
            for (int nt = 0; nt < 4; nt++) {
                qac[mt][nt] = (f32x4){0.f, 0.f, 0.f, 0.f};
                sac[mt][nt] = (f32x4){0.f, 0.f, 0.f, 0.f};
            }
#pragma unroll
        for (int kt = 0; kt < 8; kt++) {
            bf16x8 af[2];
#pragma unroll
            for (int mt = 0; mt < 2; mt++)
                af[mt] = *(const bf16x8*)&aeB[mt * 16 + lr][kt * 32 + (quad << 3)];
#pragma unroll
            for (int nt = 0; nt < 4; nt++) {
                bf16x8 bq = Bq[(kt * 16 + (wv * 4 + nt)) * 64 + ln];
                bf16x8 bs = Bs[(kt * 16 + (wv * 4 + nt)) * 64 + ln];
#pragma unroll
                for (int mt = 0; mt < 2; mt++) {
                    qac[mt][nt] = __builtin_amdgcn_mfma_f32_16x16x32_bf16(af[mt], bq, qac[mt][nt], 0, 0, 0);
                    sac[mt][nt] = __builtin_amdgcn_mfma_f32_16x16x32_bf16(af[mt], bs, sac[mt][nt], 0, 0, 0);
                }
            }
        }
#pragma unroll
        for (int nt = 0; nt < 4; nt++) {
            int d = wv * 64 + nt * 16 + lr;
            float bias = W[W_H1B + d];
#pragma unroll
            for (int mt = 0; mt < 2; mt++)
#pragma unroll
                for (int reg = 0; reg < 4; reg++) {
                    int m = mt * 16 + quad * 4 + reg;
                    qws[(r0 + m) * 256 + d]  = qac[mt][nt][reg];
                    s1ws[(r0 + m) * 256 + d] = sac[mt][nt][reg] + bias;
                }
        }
    }
}

// ---------------- K2: edge features (7) + goal polar (3) ----------------
__global__ void k_edges(const void* emb, const int* flagp, float* sews, void* out) {
    int flag = flagp[0];
    int idx = blockIdx.x * 256 + threadIdx.x;
    if (idx >= R_TOT * NJ) return;
    int r = idx / NJ, jp = idx - r * NJ;
    int b = r >> 5, i = r & 31;
    int j = jp + (jp >= i ? 1 : 0);
    int ei = r * 11, ej = (b * 32 + j) * 11;
    float pix = ldin(emb, ei + 0, flag), piy = ldin(emb, ei + 1, flag);
    float hix = ldin(emb, ei + 2, flag), hiy = ldin(emb, ei + 3, flag);
    float pjx = ldin(emb, ej + 0, flag), pjy = ldin(emb, ej + 1, flag);
    float hjx = ldin(emb, ej + 2, flag), hjy = ldin(emb, ej + 3, flag);
    float ajx = ldin(emb, ej + 7, flag), ajy = ldin(emb, ej + 8, flag);
    float gjx = ldin(emb, ej + 9, flag), gjy = ldin(emb, ej + 10, flag);
    float dx = pjx - pix, dy = pjy - piy;
    float dist = sqrtf(dx * dx + dy * dy);
    float hai = atan2f(hiy, hix);
    float ang = atan2f(dy, dx) - hai;
    float gx = gjx - pix, gy = gjy - piy;
    float gdist = sqrtf(gx * gx + gy * gy);
    float gang = atan2f(gy, gx) - hai;
    float* o = sews + idx * 10;
    o[0] = dist * (1.f / 12.f);
    o[1] = cosf(ang); o[2] = sinf(ang);
    o[3] = hjx; o[4] = hjy; o[5] = ajx; o[6] = ajy;
    o[7] = gdist; o[8] = cosf(gang); o[9] = sinf(gang);
    stout(out, OUT2 + idx, dist, flag);
}

// ---------------- K3: hard MLP via MFMA + gumbel ----------------
__global__ __launch_bounds__(256) void k_hard(const float* s1ws, const float* sews, const float* W,
                                              const void* gum, const int* flagp,
                                              float* hwws, void* out) {
    int flag = flagp[0];
    int r = blockIdx.x;
    __shared__ unsigned short a1[32][264];
    __shared__ float edg[32][8];
    __shared__ float pj0[4][32];
    __shared__ float pj1[4][32];
    int tid = threadIdx.x;
    {
        int j = tid >> 3, t = tid & 7;
        float v = 0.f;
        if (j < NJ && t < 7) v = sews[(r * NJ + j) * 10 + t];
        edg[j][t] = v;
    }
    __syncthreads();
    float w1e[7];
#pragma unroll
    for (int t = 0; t < 7; t++) w1e[t] = W[W_H1W + tid * 263 + 256 + t];
    float s1c = s1ws[r * 256 + tid];
    for (int j = 0; j < 32; j++) {
        float v = s1c;
#pragma unroll
        for (int t = 0; t < 7; t++) v += w1e[t] * edg[j][t];
        a1[j][tid] = f2bbits(fmaxf(v, 0.f));
    }
    __syncthreads();
    int wv = tid >> 6, ln = tid & 63;
    int lr = ln & 15, quad = ln >> 4;
    const bf16x8* Bp = (const bf16x8*)(W + W_H2WT);
    f32x4 acc[2][4];
#pragma unroll
    for (int mt = 0; mt < 2; mt++)
#pragma unroll
        for (int nt = 0; nt < 4; nt++) acc[mt][nt] = (f32x4){0.f, 0.f, 0.f, 0.f};
#pragma unroll
    for (int kt = 0; kt < 8; kt++) {
        bf16x8 af[2];
#pragma unroll
        for (int mt = 0; mt < 2; mt++)
            af[mt] = *(const bf16x8*)&a1[mt * 16 + lr][kt * 32 + (quad << 3)];
#pragma unroll
        for (int nt = 0; nt < 4; nt++) {
            bf16x8 bfr = Bp[(kt * 16 + (wv * 4 + nt)) * 64 + ln];
#pragma unroll
            for (int mt = 0; mt < 2; mt++)
                acc[mt][nt] = __builtin_amdgcn_mfma_f32_16x16x32_bf16(af[mt], bfr, acc[mt][nt], 0, 0, 0);
        }
    }
    float he0v[4], he1v[4], b2v[4];
#pragma unroll
    for (int nt = 0; nt < 4; nt++) {
        int d = wv * 64 + nt * 16 + lr;
        he0v[nt] = W[W_HEW + d];
        he1v[nt] = W[W_HEW + 256 + d];
        b2v[nt]  = W[W_H2B + d];
    }
    float cb0 = 0.f, cb1 = 0.f;
#pragma unroll
    for (int nt = 0; nt < 4; nt++) { cb0 += he0v[nt] * b2v[nt]; cb1 += he1v[nt] * b2v[nt]; }
#pragma unroll
    for (int mt = 0; mt < 2; mt++) {
#pragma unroll
        for (int reg = 0; reg < 4; reg++) {
            float p0 = cb0, p1 = cb1;
#pragma unroll
            for (int nt = 0; nt < 4; nt++) {
                float v = acc[mt][nt][reg];
                p0 += he0v[nt] * v;
                p1 += he1v[nt] * v;
            }
#pragma unroll
            for (int s = 1; s <= 8; s <<= 1) {
                p0 += __shfl_xor(p0, s, 64);
                p1 += __shfl_xor(p1, s, 64);
            }
            if (lr == 0) {
                int j = mt * 16 + quad * 4 + reg;
                pj0[wv][j] = p0;
                pj1[wv][j] = p1;
            }
        }
    }
    __syncthreads();
    if (tid < NJ) {
        int j = tid;
        float p0 = pj0[0][j] + pj0[1][j] + pj0[2][j] + pj0[3][j];
        float p1 = pj1[0][j] + pj1[1][j] + pj1[2][j] + pj1[3][j];
        float l0 = p0 + W[W_HEB + 0], l1 = p1 + W[W_HEB + 1];
        float u0 = ldin(gum, (r * NJ + j) * 2 + 0, flag);
        float u1 = ldin(gum, (r * NJ + j) * 2 + 1, flag);
        float g0 = -logf(-logf(u0 + 1e-10f) + 1e-10f);
        float g1 = -logf(-logf(u1 + 1e-10f) + 1e-10f);
        float dl = ((l1 + g1) - (l0 + g0)) * 2.0f;  // / tau (=0.5)
        float hwv = 1.f / (1.f + expf(-dl));
        stout(out, OUT1 + r * NJ + j, l1, flag);
        stout(out, OUT4 + r * NJ + j, hwv, flag);
        hwws[r * NJ + j] = hwv;
    }
}

// ---------------- K4: attention + softmax + combined + x + entropy + comb_w ----------------
__global__ __launch_bounds__(256) void k_attn(const float* qws, const float* sews, const float* hwws,
                                              const float* W, const int* flagp,
                                              float* xws, float* entws, void* out) {
    int flag = flagp[0];
    int r = blockIdx.x;
    __shared__ float qL[256];
    __shared__ float seL[NJ][10];
    __shared__ float KL[NJ][260];
    __shared__ float sL[32];
    __shared__ float cL[32];
    int tid = threadIdx.x;
    qL[tid] = qws[r * 256 + tid];
    for (int idx = tid; idx < NJ * 10; idx += 256) ((float*)seL)[idx] = sews[r * NJ * 10 + idx];
    __syncthreads();
    float kwr[10];
#pragma unroll
    for (int t = 0; t < 10; t++) kwr[t] = W[W_KW + tid * 10 + t];
    for (int j = 0; j < NJ; j++) {
        float v = 0.f;
#pragma unroll
        for (int t = 0; t < 10; t++) v += kwr[t] * seL[j][t];
        KL[j][tid] = v;
    }
    __syncthreads();
    int wv = tid >> 6, ln = tid & 63;
#pragma unroll
    for (int jj = 0; jj < 8; jj++) {
        int j = 8 * wv + jj;
        float p = 0.f;
        if (j < NJ) {
#pragma unroll
            for (int k2 = 0; k2 < 4; k2++) {
                int d = ln + 64 * k2;
                p += qL[d] * KL[j][d];
            }
        }
#pragma unroll
        for (int s = 32; s >= 1; s >>= 1) p += __shfl_xor(p, s, 64);
        if (j < NJ && ln == 0) sL[j] = p * (1.f / 16.f);
    }
    __syncthreads();
    if (wv == 0) {
        float sc = (ln < NJ) ? sL[ln] : -1e30f;
        float m = sc;
#pragma unroll
        for (int s = 32; s >= 1; s >>= 1) m = fmaxf(m, __shfl_xor(m, s, 64));
        float e = (ln < NJ) ? expf(sc - m) : 0.f;
        float sum = e;
#pragma unroll
        for (int s = 32; s >= 1; s >>= 1) sum += __shfl_xor(sum, s, 64);
        float sw = e / sum;
        float hv = (ln < NJ) ? hwws[r * NJ + ln] : 0.f;
        float cmb = sw * hv;
        if (ln < NJ) {
            cL[ln] = cmb;
            stout(out, OUT5 + r * NJ + ln, cmb, flag);
        }
        float csum = cmb;
#pragma unroll
        for (int s = 32; s >= 1; s >>= 1) csum += __shfl_xor(csum, s, 64);
        float cwn = cmb / (csum + 1e-6f);
        float et = (ln < NJ) ? -cwn * logf(cwn + 1e-6f) : 0.f;
#pragma unroll
        for (int s = 32; s >= 1; s >>= 1) et += __shfl_xor(et, s, 64);
        if (ln == 0) entws[r] = et;
    }
    __syncthreads();
    float vwr[10];
#pragma unroll
    for (int t = 0; t < 10; t++) vwr[t] = W[W_VW + tid * 10 + t];
    float vbv = W[W_VB + tid];
    float x = 0.f;
    for (int j = 0; j < NJ; j++) {
        float v = vbv;
#pragma unroll
        for (int t = 0; t < 10; t++) v += vwr[t] * seL[j][t];
        v = fmaxf(v, 0.f);
        x += v * cL[j];
    }
    xws[r * 256 + tid] = x;
}

// ---------------- K5: decoder ----------------
__global__ __launch_bounds__(256) void k_dec(const float* aews, const float* xws, const float* W,
                                             const int* flagp, void* out) {
    int flag = flagp[0];
    int r0 = blockIdx.x * 8;
    __shared__ float finL[8][516];
    int tid = threadIdx.x;
    for (int idx = tid; idx < 8 * 256; idx += 256) {
        int s = idx >> 8, c = idx & 255;
        finL[s][c] = aews[(r0 + s) * 256 + c];
        finL[s][256 + c] = xws[(r0 + s) * 256 + c];
    }
    __syncthreads();
    const float* decT = W + W_DECWT;
    float acc[8][2];
#pragma unroll
    for (int s = 0; s < 8; s++) { acc[s][0] = 0.f; acc[s][1] = 0.f; }
    for (int c = 0; c < 512; c++) {
        float2 w2 = *(const float2*)(decT + c * 512 + 2 * tid);
#pragma unroll
        for (int s = 0; s < 8; s++) {
            float f = finL[s][c];
            acc[s][0] += w2.x * f;
            acc[s][1] += w2.y * f;
        }
    }
    float b0 = W[W_DECB + 2 * tid], b1 = W[W_DECB + 2 * tid + 1];
#pragma unroll
    for (int s = 0; s < 8; s++) {
        stout(out, OUT0 + (r0 + s) * 512 + 2 * tid,     acc[s][0] + b0, flag);
        stout(out, OUT0 + (r0 + s) * 512 + 2 * tid + 1, acc[s][1] + b1, flag);
    }
}

// ---------------- K6: entropy mean ----------------
__global__ void k_ent(const float* entws, const int* flagp, void* out) {
    __shared__ float red[4];
    int tid = threadIdx.x;
    float s = 0.f;
    for (int i = tid; i < R_TOT; i += 256) s += entws[i];
#pragma unroll
    for (int m = 32; m >= 1; m >>= 1) s += __shfl_xor(s, m, 64);
    if ((tid & 63) == 0) red[tid >> 6] = s;
    __syncthreads();
    if (tid == 0) {
        float t = red[0] + red[1] + red[2] + red[3];
        stout(out, OUT3, t / (float)R_TOT, flagp[0]);
    }
}

// ---------------- launch ----------------
extern "C" void kernel_launch(void* const* d_in, const int* in_sizes, int n_in,
                              void* d_out, int out_size, void* d_ws, size_t ws_size,
                              hipStream_t stream) {
    const void* emb  = d_in[0];
    const void* gum  = d_in[1];
    const void* e1w  = d_in[2];
    const void* e1b  = d_in[3];
    const void* e2w  = d_in[4];
    const void* e2b  = d_in[5];
    const void* h1w  = d_in[6];
    const void* h1b  = d_in[7];
    const void* h2w  = d_in[8];
    const void* h2b  = d_in[9];
    const void* hew  = d_in[10];
    const void* heb  = d_in[11];
    const void* qw   = d_in[12];
    const void* kw   = d_in[13];
    const void* vw   = d_in[14];
    const void* vb   = d_in[15];
    const void* decw = d_in[16];
    const void* decb = d_in[17];

    float* wsf = (float*)d_ws;
    float* aews = wsf + OFF_AE;
    float* qws  = wsf + OFF_Q;
    float* s1ws = wsf + OFF_S1;
    float* sews = wsf + OFF_SE;
    float* hwws = wsf + OFF_HW;
    float* entw = wsf + OFF_ENT;
    float* xws  = wsf + OFF_X;
    float* W    = wsf + OFF_W;
    int* flagp  = (int*)(wsf + OFF_FLAG);

    hipLaunchKernelGGL(k_detect, dim3(1), dim3(64), 0, stream, emb, flagp);
    hipLaunchKernelGGL(k_conv, dim3(2048), dim3(256), 0, stream,
                       e1w, e1b, e2w, e2b, h1w, h1b, h2w, h2b, hew, heb,
                       qw, kw, vw, vb, decw, decb, W, flagp);
    hipLaunchKernelGGL(k_embed, dim3(128), dim3(256), 0, stream, emb, W, flagp, aews, qws, s1ws);
    hipLaunchKernelGGL(k_edges, dim3(496), dim3(256), 0, stream, emb, flagp, sews, d_out);
    hipLaunchKernelGGL(k_hard, dim3(4096), dim3(256), 0, stream,
                       s1ws, sews, W, gum, flagp, hwws, d_out);
    hipLaunchKernelGGL(k_attn, dim3(4096), dim3(256), 0, stream,
                       qws, sews, hwws, W, flagp, xws, entw, d_out);
    hipLaunchKernelGGL(k_dec, dim3(512), dim3(256), 0, stream, aews, xws, W, flagp, d_out);
    hipLaunchKernelGGL(k_ent, dim3(1), dim3(256), 0, stream, entw, flagp, d_out);
}

// Round 6
// 228.272 us; speedup vs baseline: 2.3146x; 1.1883x over previous
//
#include <hip/hip_runtime.h>
#include <hip/hip_bf16.h>
#include <math.h>

typedef __hip_bfloat16 bf16;
typedef short bf16x8 __attribute__((ext_vector_type(8)));
typedef float f32x4 __attribute__((ext_vector_type(4)));

#define R_TOT 4096   // B*N
#define NJ 31

// ---- workspace layout (float element offsets) ----
#define OFF_AE   0
#define OFF_Q    1048576
#define OFF_S1   2097152
#define OFF_SE   3145728
#define OFF_HW   4415488
#define OFF_ENT  4542464
#define OFF_X    4546560
#define OFF_W    5595136   // canonical weights base
// relative to W:
#define W_E1W   0
#define W_E1B   640
#define W_E2P   768        // e2 B-pack: 32768 bf16
#define W_E2B   33536
#define W_H1W   33792
#define W_H1B   101120
#define W_H2WT  101376     // h2 B-pack: 65536 bf16
#define W_H2B   166912
#define W_HEW   167168
#define W_HEB   167680
#define W_QP    167684     // q B-pack: 65536 bf16
#define W_S1P   200452     // s1 B-pack: 65536 bf16
#define W_KW    233220
#define W_VW    235780
#define W_VB    238340
#define W_DECWT 238596     // dec B-pack: 262144 bf16 (reuses old fp32 decT slot)
#define W_DECB  500740
#define OFF_FLAG 6100992   // int flag

// ---- output element offsets ----
#define OUT0 0
#define OUT1 2097152
#define OUT2 2224128
#define OUT3 2351104
#define OUT4 2351105
#define OUT5 2478081

__device__ __forceinline__ float b2f(bf16 x) { return __bfloat162float(x); }
__device__ __forceinline__ float ldin(const void* p, int i, int flag) {
    return flag ? b2f(((const bf16*)p)[i]) : ((const float*)p)[i];
}
__device__ __forceinline__ void stout(void* p, int i, float v, int flag) {
    if (flag) ((bf16*)p)[i] = __float2bfloat16(v);
    else      ((float*)p)[i] = v;
}
__device__ __forceinline__ unsigned short f2bbits(float v) {
    bf16 h = __float2bfloat16(v);
    return *(unsigned short*)&h;
}

// ---------------- K0: dtype detector ----------------
__global__ void k_detect(const void* emb, int* flagp) {
    int ln = threadIdx.x;
    float x = ((const float*)emb)[ln];
    int sane = (x == x) && (fabsf(x) < 1e20f);
    unsigned long long m = __ballot(sane);
    if (ln == 0) flagp[0] = (__popcll(m) == 64) ? 0 : 1;  // 0=fp32, 1=bf16
}

// ---------------- K0b: convert weights: fp32 canon + MFMA B-packs ----------------
__global__ __launch_bounds__(256) void k_conv(
        const void* e1w, const void* e1b, const void* e2w, const void* e2b,
        const void* h1w, const void* h1b, const void* h2w, const void* h2b,
        const void* hew, const void* heb, const void* qw,  const void* kw,
        const void* vw,  const void* vb,  const void* decw,const void* decb,
        float* W, const int* flagp) {
    int flag = flagp[0];
    int idx = blockIdx.x * 256 + threadIdx.x;
    if (idx < 65536) {
        // h2 B-pack: idx = ((kt*16+nt)*64+lane)*8+jj ; B[k][n] = hm2_w[n*256+k]
        int jj   = idx & 7;
        int lane = (idx >> 3) & 63;
        int tile = idx >> 9;
        int nt = tile & 15, kt = tile >> 4;
        int n = nt * 16 + (lane & 15);
        int c = kt * 32 + ((lane >> 4) << 3) + jj;
        ((unsigned short*)(W + W_H2WT))[idx] = f2bbits(ldin(h2w, n * 256 + c, flag));
    }
    if (idx < 262144) {
        // dec B-pack: idx = ((kt*32+nt)*64+lane)*8+jj ; B[k][n] = dec_w[n*512+k]
        int jj   = idx & 7;
        int lane = (idx >> 3) & 63;
        int tile = idx >> 9;          // 0..511
        int nt = tile & 31, kt = tile >> 5;
        int n = nt * 16 + (lane & 15);
        int k = kt * 32 + ((lane >> 4) << 3) + jj;
        ((unsigned short*)(W + W_DECWT))[idx] = f2bbits(ldin(decw, n * 512 + k, flag));
    }
    int j = idx - 262144;
    if (j >= 0 && j < 163840) {  // MFMA B-packs for e2 / q / s1
        int p;
        const void* src; int ldm, Wdst;
        if (j < 32768)      { p = j;          src = e2w; ldm = 128; Wdst = W_E2P; }
        else if (j < 98304) { p = j - 32768;  src = qw;  ldm = 256; Wdst = W_QP;  }
        else                { p = j - 98304;  src = h1w; ldm = 263; Wdst = W_S1P; }
        int jj   = p & 7;
        int lane = (p >> 3) & 63;
        int tile = p >> 9;
        int nt = tile & 15, kt = tile >> 4;
        int n = nt * 16 + (lane & 15);
        int k = kt * 32 + ((lane >> 4) << 3) + jj;
        ((unsigned short*)(W + Wdst))[p] = f2bbits(ldin(src, n * ldm + k, flag));
    } else if (j >= 163840 && j < 239618) {   // fp32 canon for the rest
        int q2 = j - 163840;
        if      (q2 < 640)   W[W_E1W  + q2]           = ldin(e1w,  q2,          flag);
        else if (q2 < 768)   W[W_E1B  + (q2 - 640)]   = ldin(e1b,  q2 - 640,    flag);
        else if (q2 < 1024)  W[W_E2B  + (q2 - 768)]   = ldin(e2b,  q2 - 768,    flag);
        else if (q2 < 68352) W[W_H1W  + (q2 - 1024)]  = ldin(h1w,  q2 - 1024,   flag);
        else if (q2 < 68608) W[W_H1B  + (q2 - 68352)] = ldin(h1b,  q2 - 68352,  flag);
        else if (q2 < 68864) W[W_H2B  + (q2 - 68608)] = ldin(h2b,  q2 - 68608,  flag);
        else if (q2 < 69376) W[W_HEW  + (q2 - 68864)] = ldin(hew,  q2 - 68864,  flag);
        else if (q2 < 69378) W[W_HEB  + (q2 - 69376)] = ldin(heb,  q2 - 69376,  flag);
        else if (q2 < 71938) W[W_KW   + (q2 - 69378)] = ldin(kw,   q2 - 69378,  flag);
        else if (q2 < 74498) W[W_VW   + (q2 - 71938)] = ldin(vw,   q2 - 71938,  flag);
        else if (q2 < 74754) W[W_VB   + (q2 - 74498)] = ldin(vb,   q2 - 74498,  flag);
        else                 W[W_DECB + (q2 - 74754)] = ldin(decb, q2 - 74754,  flag);
    }
}

// ---------------- K1: embed MLP + q + s1, all via MFMA ----------------
__global__ __launch_bounds__(256) void k_embed(const void* emb, const float* W, const int* flagp,
                                               float* aews, float* qws, float* s1ws) {
    int flag = flagp[0];
    int r0 = blockIdx.x * 32;   // 128 blocks
    __shared__ float embL[32][12];
    __shared__ unsigned short hB[32][136];
    __shared__ unsigned short aeB[32][264];
    int tid = threadIdx.x;
    for (int idx = tid; idx < 32 * 11; idx += 256) {
        int s = idx / 11, t = idx % 11;
        embL[s][t] = ldin(emb, (r0 + s) * 11 + t, flag);
    }
    __syncthreads();
    for (int idx = tid; idx < 32 * 128; idx += 256) {
        int s = idx >> 7, jo = idx & 127;
        float v = W[W_E1B + jo];
#pragma unroll
        for (int t = 0; t < 5; t++) v += W[W_E1W + jo * 5 + t] * embL[s][4 + t];
        hB[s][jo] = f2bbits(v > 0.f ? v : 0.01f * v);
    }
    __syncthreads();
    int wv = tid >> 6, ln = tid & 63;
    int lr = ln & 15, quad = ln >> 4;
    {
        const bf16x8* Bp = (const bf16x8*)(W + W_E2P);
        f32x4 acc[2][4];
#pragma unroll
        for (int mt = 0; mt < 2; mt++)
#pragma unroll
            for (int nt = 0; nt < 4; nt++) acc[mt][nt] = (f32x4){0.f, 0.f, 0.f, 0.f};
#pragma unroll
        for (int kt = 0; kt < 4; kt++) {
            bf16x8 af[2];
#pragma unroll
            for (int mt = 0; mt < 2; mt++)
                af[mt] = *(const bf16x8*)&hB[mt * 16 + lr][kt * 32 + (quad << 3)];
#pragma unroll
            for (int nt = 0; nt < 4; nt++) {
                bf16x8 bfr = Bp[(kt * 16 + (wv * 4 + nt)) * 64 + ln];
#pragma unroll
                for (int mt = 0; mt < 2; mt++)
                    acc[mt][nt] = __builtin_amdgcn_mfma_f32_16x16x32_bf16(af[mt], bfr, acc[mt][nt], 0, 0, 0);
            }
        }
#pragma unroll
        for (int nt = 0; nt < 4; nt++) {
            int d = wv * 64 + nt * 16 + lr;
            float bias = W[W_E2B + d];
#pragma unroll
            for (int mt = 0; mt < 2; mt++)
#pragma unroll
                for (int reg = 0; reg < 4; reg++) {
                    int m = mt * 16 + quad * 4 + reg;
                    float v = acc[mt][nt][reg] + bias;
                    v = v > 0.f ? v : 0.01f * v;
                    aeB[m][d] = f2bbits(v);
                    aews[(r0 + m) * 256 + d] = v;
                }
        }
    }
    __syncthreads();
    {
        const bf16x8* Bq = (const bf16x8*)(W + W_QP);
        const bf16x8* Bs = (const bf16x8*)(W + W_S1P);
        f32x4 qac[2][4], sac[2][4];
#pragma unroll
        for (int mt = 0; mt < 2; mt++)
#pragma unroll
            for (int nt = 0; nt < 4; nt++) {
                qac[mt][nt] = (f32x4){0.f, 0.f, 0.f, 0.f};
                sac[mt][nt] = (f32x4){0.f, 0.f, 0.f, 0.f};
            }
#pragma unroll
        for (int kt = 0; kt < 8; kt++) {
            bf16x8 af[2];
#pragma unroll
            for (int mt = 0; mt < 2; mt++)
                af[mt] = *(const bf16x8*)&aeB[mt * 16 + lr][kt * 32 + (quad << 3)];
#pragma unroll
            for (int nt = 0; nt < 4; nt++) {
                bf16x8 bq = Bq[(kt * 16 + (wv * 4 + nt)) * 64 + ln];
                bf16x8 bs = Bs[(kt * 16 + (wv * 4 + nt)) * 64 + ln];
#pragma unroll
                for (int mt = 0; mt < 2; mt++) {
                    qac[mt][nt] = __builtin_amdgcn_mfma_f32_16x16x32_bf16(af[mt], bq, qac[mt][nt], 0, 0, 0);
                    sac[mt][nt] = __builtin_amdgcn_mfma_f32_16x16x32_bf16(af[mt], bs, sac[mt][nt], 0, 0, 0);
                }
            }
        }
#pragma unroll
        for (int nt = 0; nt < 4; nt++) {
            int d = wv * 64 + nt * 16 + lr;
            float bias = W[W_H1B + d];
#pragma unroll
            for (int mt = 0; mt < 2; mt++)
#pragma unroll
                for (int reg = 0; reg < 4; reg++) {
                    int m = mt * 16 + quad * 4 + reg;
                    qws[(r0 + m) * 256 + d]  = qac[mt][nt][reg];
                    s1ws[(r0 + m) * 256 + d] = sac[mt][nt][reg] + bias;
                }
        }
    }
}

// ---------------- K2: edge features (7) + goal polar (3) ----------------
__global__ void k_edges(const void* emb, const int* flagp, float* sews, void* out) {
    int flag = flagp[0];
    int idx = blockIdx.x * 256 + threadIdx.x;
    if (idx >= R_TOT * NJ) return;
    int r = idx / NJ, jp = idx - r * NJ;
    int b = r >> 5, i = r & 31;
    int j = jp + (jp >= i ? 1 : 0);
    int ei = r * 11, ej = (b * 32 + j) * 11;
    float pix = ldin(emb, ei + 0, flag), piy = ldin(emb, ei + 1, flag);
    float hix = ldin(emb, ei + 2, flag), hiy = ldin(emb, ei + 3, flag);
    float pjx = ldin(emb, ej + 0, flag), pjy = ldin(emb, ej + 1, flag);
    float hjx = ldin(emb, ej + 2, flag), hjy = ldin(emb, ej + 3, flag);
    float ajx = ldin(emb, ej + 7, flag), ajy = ldin(emb, ej + 8, flag);
    float gjx = ldin(emb, ej + 9, flag), gjy = ldin(emb, ej + 10, flag);
    float dx = pjx - pix, dy = pjy - piy;
    float dist = sqrtf(dx * dx + dy * dy);
    float hai = atan2f(hiy, hix);
    float ang = atan2f(dy, dx) - hai;
    float gx = gjx - pix, gy = gjy - piy;
    float gdist = sqrtf(gx * gx + gy * gy);
    float gang = atan2f(gy, gx) - hai;
    float* o = sews + idx * 10;
    o[0] = dist * (1.f / 12.f);
    o[1] = cosf(ang); o[2] = sinf(ang);
    o[3] = hjx; o[4] = hjy; o[5] = ajx; o[6] = ajy;
    o[7] = gdist; o[8] = cosf(gang); o[9] = sinf(gang);
    stout(out, OUT2 + idx, dist, flag);
}

// ---------------- K3: hard MLP via MFMA + gumbel ----------------
__global__ __launch_bounds__(256) void k_hard(const float* s1ws, const float* sews, const float* W,
                                              const void* gum, const int* flagp,
                                              float* hwws, void* out) {
    int flag = flagp[0];
    int r = blockIdx.x;
    __shared__ unsigned short a1[32][264];
    __shared__ float edg[32][8];
    __shared__ float pj0[4][32];
    __shared__ float pj1[4][32];
    int tid = threadIdx.x;
    {
        int j = tid >> 3, t = tid & 7;
        float v = 0.f;
        if (j < NJ && t < 7) v = sews[(r * NJ + j) * 10 + t];
        edg[j][t] = v;
    }
    __syncthreads();
    float w1e[7];
#pragma unroll
    for (int t = 0; t < 7; t++) w1e[t] = W[W_H1W + tid * 263 + 256 + t];
    float s1c = s1ws[r * 256 + tid];
    for (int j = 0; j < 32; j++) {
        float v = s1c;
#pragma unroll
        for (int t = 0; t < 7; t++) v += w1e[t] * edg[j][t];
        a1[j][tid] = f2bbits(fmaxf(v, 0.f));
    }
    __syncthreads();
    int wv = tid >> 6, ln = tid & 63;
    int lr = ln & 15, quad = ln >> 4;
    const bf16x8* Bp = (const bf16x8*)(W + W_H2WT);
    f32x4 acc[2][4];
#pragma unroll
    for (int mt = 0; mt < 2; mt++)
#pragma unroll
        for (int nt = 0; nt < 4; nt++) acc[mt][nt] = (f32x4){0.f, 0.f, 0.f, 0.f};
#pragma unroll
    for (int kt = 0; kt < 8; kt++) {
        bf16x8 af[2];
#pragma unroll
        for (int mt = 0; mt < 2; mt++)
            af[mt] = *(const bf16x8*)&a1[mt * 16 + lr][kt * 32 + (quad << 3)];
#pragma unroll
        for (int nt = 0; nt < 4; nt++) {
            bf16x8 bfr = Bp[(kt * 16 + (wv * 4 + nt)) * 64 + ln];
#pragma unroll
            for (int mt = 0; mt < 2; mt++)
                acc[mt][nt] = __builtin_amdgcn_mfma_f32_16x16x32_bf16(af[mt], bfr, acc[mt][nt], 0, 0, 0);
        }
    }
    float he0v[4], he1v[4], b2v[4];
#pragma unroll
    for (int nt = 0; nt < 4; nt++) {
        int d = wv * 64 + nt * 16 + lr;
        he0v[nt] = W[W_HEW + d];
        he1v[nt] = W[W_HEW + 256 + d];
        b2v[nt]  = W[W_H2B + d];
    }
    float cb0 = 0.f, cb1 = 0.f;
#pragma unroll
    for (int nt = 0; nt < 4; nt++) { cb0 += he0v[nt] * b2v[nt]; cb1 += he1v[nt] * b2v[nt]; }
#pragma unroll
    for (int mt = 0; mt < 2; mt++) {
#pragma unroll
        for (int reg = 0; reg < 4; reg++) {
            float p0 = cb0, p1 = cb1;
#pragma unroll
            for (int nt = 0; nt < 4; nt++) {
                float v = acc[mt][nt][reg];
                p0 += he0v[nt] * v;
                p1 += he1v[nt] * v;
            }
#pragma unroll
            for (int s = 1; s <= 8; s <<= 1) {
                p0 += __shfl_xor(p0, s, 64);
                p1 += __shfl_xor(p1, s, 64);
            }
            if (lr == 0) {
                int j = mt * 16 + quad * 4 + reg;
                pj0[wv][j] = p0;
                pj1[wv][j] = p1;
            }
        }
    }
    __syncthreads();
    if (tid < NJ) {
        int j = tid;
        float p0 = pj0[0][j] + pj0[1][j] + pj0[2][j] + pj0[3][j];
        float p1 = pj1[0][j] + pj1[1][j] + pj1[2][j] + pj1[3][j];
        float l0 = p0 + W[W_HEB + 0], l1 = p1 + W[W_HEB + 1];
        float u0 = ldin(gum, (r * NJ + j) * 2 + 0, flag);
        float u1 = ldin(gum, (r * NJ + j) * 2 + 1, flag);
        float g0 = -logf(-logf(u0 + 1e-10f) + 1e-10f);
        float g1 = -logf(-logf(u1 + 1e-10f) + 1e-10f);
        float dl = ((l1 + g1) - (l0 + g0)) * 2.0f;  // / tau (=0.5)
        float hwv = 1.f / (1.f + expf(-dl));
        stout(out, OUT1 + r * NJ + j, l1, flag);
        stout(out, OUT4 + r * NJ + j, hwv, flag);
        hwws[r * NJ + j] = hwv;
    }
}

// ---------------- K4: attention + softmax + combined + x + entropy + comb_w ----------------
__global__ __launch_bounds__(256) void k_attn(const float* qws, const float* sews, const float* hwws,
                                              const float* W, const int* flagp,
                                              float* xws, float* entws, void* out) {
    int flag = flagp[0];
    int r = blockIdx.x;
    __shared__ float qL[256];
    __shared__ float seL[NJ][10];
    __shared__ float KL[NJ][260];
    __shared__ float sL[32];
    __shared__ float cL[32];
    int tid = threadIdx.x;
    qL[tid] = qws[r * 256 + tid];
    for (int idx = tid; idx < NJ * 10; idx += 256) ((float*)seL)[idx] = sews[r * NJ * 10 + idx];
    __syncthreads();
    float kwr[10];
#pragma unroll
    for (int t = 0; t < 10; t++) kwr[t] = W[W_KW + tid * 10 + t];
    for (int j = 0; j < NJ; j++) {
        float v = 0.f;
#pragma unroll
        for (int t = 0; t < 10; t++) v += kwr[t] * seL[j][t];
        KL[j][tid] = v;
    }
    __syncthreads();
    int wv = tid >> 6, ln = tid & 63;
#pragma unroll
    for (int jj = 0; jj < 8; jj++) {
        int j = 8 * wv + jj;
        float p = 0.f;
        if (j < NJ) {
#pragma unroll
            for (int k2 = 0; k2 < 4; k2++) {
                int d = ln + 64 * k2;
                p += qL[d] * KL[j][d];
            }
        }
#pragma unroll
        for (int s = 32; s >= 1; s >>= 1) p += __shfl_xor(p, s, 64);
        if (j < NJ && ln == 0) sL[j] = p * (1.f / 16.f);
    }
    __syncthreads();
    if (wv == 0) {
        float sc = (ln < NJ) ? sL[ln] : -1e30f;
        float m = sc;
#pragma unroll
        for (int s = 32; s >= 1; s >>= 1) m = fmaxf(m, __shfl_xor(m, s, 64));
        float e = (ln < NJ) ? expf(sc - m) : 0.f;
        float sum = e;
#pragma unroll
        for (int s = 32; s >= 1; s >>= 1) sum += __shfl_xor(sum, s, 64);
        float sw = e / sum;
        float hv = (ln < NJ) ? hwws[r * NJ + ln] : 0.f;
        float cmb = sw * hv;
        if (ln < NJ) {
            cL[ln] = cmb;
            stout(out, OUT5 + r * NJ + ln, cmb, flag);
        }
        float csum = cmb;
#pragma unroll
        for (int s = 32; s >= 1; s >>= 1) csum += __shfl_xor(csum, s, 64);
        float cwn = cmb / (csum + 1e-6f);
        float et = (ln < NJ) ? -cwn * logf(cwn + 1e-6f) : 0.f;
#pragma unroll
        for (int s = 32; s >= 1; s >>= 1) et += __shfl_xor(et, s, 64);
        if (ln == 0) entws[r] = et;
    }
    __syncthreads();
    float vwr[10];
#pragma unroll
    for (int t = 0; t < 10; t++) vwr[t] = W[W_VW + tid * 10 + t];
    float vbv = W[W_VB + tid];
    float x = 0.f;
    for (int j = 0; j < NJ; j++) {
        float v = vbv;
#pragma unroll
        for (int t = 0; t < 10; t++) v += vwr[t] * seL[j][t];
        v = fmaxf(v, 0.f);
        x += v * cL[j];
    }
    xws[r * 256 + tid] = x;
}

// ---------------- K5: decoder via MFMA ----------------
// grid 512: blockIdx>>2 = row strip (32 rows), blockIdx&3 = N-quarter (128 cols)
__global__ __launch_bounds__(256) void k_dec(const float* aews, const float* xws, const float* W,
                                             const int* flagp, void* out) {
    int flag = flagp[0];
    int r0 = (blockIdx.x >> 2) * 32;
    int nq = blockIdx.x & 3;
    __shared__ unsigned short finB[32][520];
    int tid = threadIdx.x;
    for (int idx = tid; idx < 32 * 512; idx += 256) {
        int s = idx >> 9, c = idx & 511;
        float v = (c < 256) ? aews[(r0 + s) * 256 + c] : xws[(r0 + s) * 256 + (c - 256)];
        finB[s][c] = f2bbits(v);
    }
    __syncthreads();
    int wv = tid >> 6, ln = tid & 63;
    int lr = ln & 15, quad = ln >> 4;
    const bf16x8* Bp = (const bf16x8*)(W + W_DECWT);
    f32x4 acc[2][2];
#pragma unroll
    for (int mt = 0; mt < 2; mt++)
#pragma unroll
        for (int nt = 0; nt < 2; nt++) acc[mt][nt] = (f32x4){0.f, 0.f, 0.f, 0.f};
#pragma unroll
    for (int kt = 0; kt < 16; kt++) {
        bf16x8 af[2];
#pragma unroll
        for (int mt = 0; mt < 2; mt++)
            af[mt] = *(const bf16x8*)&finB[mt * 16 + lr][kt * 32 + (quad << 3)];
#pragma unroll
        for (int nt = 0; nt < 2; nt++) {
            int gnt = nq * 8 + wv * 2 + nt;
            bf16x8 bfr = Bp[(kt * 32 + gnt) * 64 + ln];
#pragma unroll
            for (int mt = 0; mt < 2; mt++)
                acc[mt][nt] = __builtin_amdgcn_mfma_f32_16x16x32_bf16(af[mt], bfr, acc[mt][nt], 0, 0, 0);
        }
    }
#pragma unroll
    for (int nt = 0; nt < 2; nt++) {
        int d = (nq * 8 + wv * 2 + nt) * 16 + lr;
        float bias = W[W_DECB + d];
#pragma unroll
        for (int mt = 0; mt < 2; mt++)
#pragma unroll
            for (int reg = 0; reg < 4; reg++) {
                int m = mt * 16 + quad * 4 + reg;
                stout(out, OUT0 + (r0 + m) * 512 + d, acc[mt][nt][reg] + bias, flag);
            }
    }
}

// ---------------- K6: entropy mean ----------------
__global__ void k_ent(const float* entws, const int* flagp, void* out) {
    __shared__ float red[4];
    int tid = threadIdx.x;
    float s = 0.f;
    for (int i = tid; i < R_TOT; i += 256) s += entws[i];
#pragma unroll
    for (int m = 32; m >= 1; m >>= 1) s += __shfl_xor(s, m, 64);
    if ((tid & 63) == 0) red[tid >> 6] = s;
    __syncthreads();
    if (tid == 0) {
        float t = red[0] + red[1] + red[2] + red[3];
        stout(out, OUT3, t / (float)R_TOT, flagp[0]);
    }
}

// ---------------- launch ----------------
extern "C" void kernel_launch(void* const* d_in, const int* in_sizes, int n_in,
                              void* d_out, int out_size, void* d_ws, size_t ws_size,
                              hipStream_t stream) {
    const void* emb  = d_in[0];
    const void* gum  = d_in[1];
    const void* e1w  = d_in[2];
    const void* e1b  = d_in[3];
    const void* e2w  = d_in[4];
    const void* e2b  = d_in[5];
    const void* h1w  = d_in[6];
    const void* h1b  = d_in[7];
    const void* h2w  = d_in[8];
    const void* h2b  = d_in[9];
    const void* hew  = d_in[10];
    const void* heb  = d_in[11];
    const void* qw   = d_in[12];
    const void* kw   = d_in[13];
    const void* vw   = d_in[14];
    const void* vb   = d_in[15];
    const void* decw = d_in[16];
    const void* decb = d_in[17];

    float* wsf = (float*)d_ws;
    float* aews = wsf + OFF_AE;
    float* qws  = wsf + OFF_Q;
    float* s1ws = wsf + OFF_S1;
    float* sews = wsf + OFF_SE;
    float* hwws = wsf + OFF_HW;
    float* entw = wsf + OFF_ENT;
    float* xws  = wsf + OFF_X;
    float* W    = wsf + OFF_W;
    int* flagp  = (int*)(wsf + OFF_FLAG);

    hipLaunchKernelGGL(k_detect, dim3(1), dim3(64), 0, stream, emb, flagp);
    hipLaunchKernelGGL(k_conv, dim3(2048), dim3(256), 0, stream,
                       e1w, e1b, e2w, e2b, h1w, h1b, h2w, h2b, hew, heb,
                       qw, kw, vw, vb, decw, decb, W, flagp);
    hipLaunchKernelGGL(k_embed, dim3(128), dim3(256), 0, stream, emb, W, flagp, aews, qws, s1ws);
    hipLaunchKernelGGL(k_edges, dim3(496), dim3(256), 0, stream, emb, flagp, sews, d_out);
    hipLaunchKernelGGL(k_hard, dim3(4096), dim3(256), 0, stream,
                       s1ws, sews, W, gum, flagp, hwws, d_out);
    hipLaunchKernelGGL(k_attn, dim3(4096), dim3(256), 0, stream,
                       qws, sews, hwws, W, flagp, xws, entw, d_out);
    hipLaunchKernelGGL(k_dec, dim3(512), dim3(256), 0, stream, aews, xws, W, flagp, d_out);
    hipLaunchKernelGGL(k_ent, dim3(1), dim3(256), 0, stream, entw, flagp, d_out);
}

// Round 7
// 223.833 us; speedup vs baseline: 2.3605x; 1.0198x over previous
//
#include <hip/hip_runtime.h>
#include <hip/hip_bf16.h>
#include <math.h>

typedef __hip_bfloat16 bf16;
typedef short bf16x8 __attribute__((ext_vector_type(8)));
typedef float f32x4 __attribute__((ext_vector_type(4)));

#define R_TOT 4096   // B*N
#define NJ 31

// ---- workspace layout (float element offsets) ----
#define OFF_AE   0
#define OFF_QK   1048576   // qk: 4096*10 floats (reuses old qws slot)
#define OFF_S1   2097152
#define OFF_SE   3145728
#define OFF_HW   4415488
#define OFF_ENT  4542464
#define OFF_X    4546560
#define OFF_W    5595136   // canonical weights base
// relative to W:
#define W_E1W   0
#define W_E1B   640
#define W_E2P   768        // e2 B-pack: 32768 bf16
#define W_E2B   33536
#define W_H1W   33792
#define W_H1B   101120
#define W_H2WT  101376     // h2 B-pack: 65536 bf16
#define W_H2B   166912
#define W_HEW   167168
#define W_HEB   167680
#define W_QP    167684     // (unused legacy q B-pack slot)
#define W_S1P   200452     // s1 B-pack: 65536 bf16
#define W_KW    233220
#define W_VW    235780
#define W_VB    238340
#define W_DECWT 238596     // dec B-pack: 262144 bf16
#define W_DECB  500740
#define W_QKM   501252     // M = qw^T@kw B-pack: 4096 bf16 (2048 floats)
#define OFF_FLAG 6100992   // int flag

// ---- output element offsets ----
#define OUT0 0
#define OUT1 2097152
#define OUT2 2224128
#define OUT3 2351104
#define OUT4 2351105
#define OUT5 2478081

__device__ __forceinline__ float b2f(bf16 x) { return __bfloat162float(x); }
__device__ __forceinline__ float ldin(const void* p, int i, int flag) {
    return flag ? b2f(((const bf16*)p)[i]) : ((const float*)p)[i];
}
__device__ __forceinline__ void stout(void* p, int i, float v, int flag) {
    if (flag) ((bf16*)p)[i] = __float2bfloat16(v);
    else      ((float*)p)[i] = v;
}
__device__ __forceinline__ unsigned short f2bbits(float v) {
    bf16 h = __float2bfloat16(v);
    return *(unsigned short*)&h;
}

// ---------------- K0: dtype detector ----------------
__global__ void k_detect(const void* emb, int* flagp) {
    int ln = threadIdx.x;
    float x = ((const float*)emb)[ln];
    int sane = (x == x) && (fabsf(x) < 1e20f);
    unsigned long long m = __ballot(sane);
    if (ln == 0) flagp[0] = (__popcll(m) == 64) ? 0 : 1;  // 0=fp32, 1=bf16
}

// ---------------- K0b: convert weights: fp32 canon + MFMA B-packs ----------------
__global__ __launch_bounds__(256) void k_conv(
        const void* e1w, const void* e1b, const void* e2w, const void* e2b,
        const void* h1w, const void* h1b, const void* h2w, const void* h2b,
        const void* hew, const void* heb, const void* qw,  const void* kw,
        const void* vw,  const void* vb,  const void* decw,const void* decb,
        float* W, const int* flagp) {
    int flag = flagp[0];
    int idx = blockIdx.x * 256 + threadIdx.x;
    if (idx < 65536) {
        // h2 B-pack: idx = ((kt*16+nt)*64+lane)*8+jj ; B[k][n] = hm2_w[n*256+k]
        int jj   = idx & 7;
        int lane = (idx >> 3) & 63;
        int tile = idx >> 9;
        int nt = tile & 15, kt = tile >> 4;
        int n = nt * 16 + (lane & 15);
        int c = kt * 32 + ((lane >> 4) << 3) + jj;
        ((unsigned short*)(W + W_H2WT))[idx] = f2bbits(ldin(h2w, n * 256 + c, flag));
    }
    if (idx < 262144) {
        // dec B-pack: idx = ((kt*32+nt)*64+lane)*8+jj ; B[k][n] = dec_w[n*512+k]
        int jj   = idx & 7;
        int lane = (idx >> 3) & 63;
        int tile = idx >> 9;          // 0..511
        int nt = tile & 31, kt = tile >> 5;
        int n = nt * 16 + (lane & 15);
        int k = kt * 32 + ((lane >> 4) << 3) + jj;
        ((unsigned short*)(W + W_DECWT))[idx] = f2bbits(ldin(decw, n * 512 + k, flag));
    }
    int j = idx - 262144;
    if (j >= 0 && j < 98304) {  // MFMA B-packs for e2 / s1
        int p;
        const void* src; int ldm, Wdst;
        if (j < 32768)      { p = j;          src = e2w; ldm = 128; Wdst = W_E2P; }
        else                { p = j - 32768;  src = h1w; ldm = 263; Wdst = W_S1P; }
        int jj   = p & 7;
        int lane = (p >> 3) & 63;
        int tile = p >> 9;
        int nt = tile & 15, kt = tile >> 4;
        int n = nt * 16 + (lane & 15);
        int k = kt * 32 + ((lane >> 4) << 3) + jj;
        ((unsigned short*)(W + Wdst))[p] = f2bbits(ldin(src, n * ldm + k, flag));
    } else if (j >= 98304 && j < 174082) {   // fp32 canon for the rest
        int q2 = j - 98304;
        if      (q2 < 640)   W[W_E1W  + q2]           = ldin(e1w,  q2,          flag);
        else if (q2 < 768)   W[W_E1B  + (q2 - 640)]   = ldin(e1b,  q2 - 640,    flag);
        else if (q2 < 1024)  W[W_E2B  + (q2 - 768)]   = ldin(e2b,  q2 - 768,    flag);
        else if (q2 < 68352) W[W_H1W  + (q2 - 1024)]  = ldin(h1w,  q2 - 1024,   flag);
        else if (q2 < 68608) W[W_H1B  + (q2 - 68352)] = ldin(h1b,  q2 - 68352,  flag);
        else if (q2 < 68864) W[W_H2B  + (q2 - 68608)] = ldin(h2b,  q2 - 68608,  flag);
        else if (q2 < 69376) W[W_HEW  + (q2 - 68864)] = ldin(hew,  q2 - 68864,  flag);
        else if (q2 < 69378) W[W_HEB  + (q2 - 69376)] = ldin(heb,  q2 - 69376,  flag);
        else if (q2 < 71938) W[W_KW   + (q2 - 69378)] = ldin(kw,   q2 - 69378,  flag);
        else if (q2 < 74498) W[W_VW   + (q2 - 71938)] = ldin(vw,   q2 - 71938,  flag);
        else if (q2 < 74754) W[W_VB   + (q2 - 74498)] = ldin(vb,   q2 - 74498,  flag);
        else                 W[W_DECB + (q2 - 74754)] = ldin(decb, q2 - 74754,  flag);
    }
}

// ---------------- K0c: M = qw^T @ kw (256x10), packed as MFMA B-fragments ----------------
__global__ __launch_bounds__(256) void k_qkm(const void* qw, const void* kw, float* W, const int* flagp) {
    int flag = flagp[0];
    int p = blockIdx.x * 256 + threadIdx.x;   // 16 blocks -> 4096 entries
    if (p >= 4096) return;
    int jj = p & 7, lane = (p >> 3) & 63, kt = p >> 9;
    int k = kt * 32 + ((lane >> 4) << 3) + jj;   // c index 0..255
    int n = lane & 15;                           // t index (10 real)
    float v = 0.f;
    if (n < 10) {
        for (int d = 0; d < 256; d++)
            v += ldin(qw, d * 256 + k, flag) * ldin(kw, d * 10 + n, flag);
    }
    ((unsigned short*)(W + W_QKM))[p] = f2bbits(v);
}

// ---------------- K1: embed MLP + s1 + qk, all via MFMA ----------------
__global__ __launch_bounds__(256) void k_embed(const void* emb, const float* W, const int* flagp,
                                               float* aews, float* qkws, float* s1ws) {
    int flag = flagp[0];
    int r0 = blockIdx.x * 32;   // 128 blocks
    __shared__ float embL[32][12];
    __shared__ unsigned short hB[32][136];
    __shared__ unsigned short aeB[32][264];
    int tid = threadIdx.x;
    for (int idx = tid; idx < 32 * 11; idx += 256) {
        int s = idx / 11, t = idx % 11;
        embL[s][t] = ldin(emb, (r0 + s) * 11 + t, flag);
    }
    __syncthreads();
    for (int idx = tid; idx < 32 * 128; idx += 256) {
        int s = idx >> 7, jo = idx & 127;
        float v = W[W_E1B + jo];
#pragma unroll
        for (int t = 0; t < 5; t++) v += W[W_E1W + jo * 5 + t] * embL[s][4 + t];
        hB[s][jo] = f2bbits(v > 0.f ? v : 0.01f * v);
    }
    __syncthreads();
    int wv = tid >> 6, ln = tid & 63;
    int lr = ln & 15, quad = ln >> 4;
    {
        const bf16x8* Bp = (const bf16x8*)(W + W_E2P);
        f32x4 acc[2][4];
#pragma unroll
        for (int mt = 0; mt < 2; mt++)
#pragma unroll
            for (int nt = 0; nt < 4; nt++) acc[mt][nt] = (f32x4){0.f, 0.f, 0.f, 0.f};
#pragma unroll
        for (int kt = 0; kt < 4; kt++) {
            bf16x8 af[2];
#pragma unroll
            for (int mt = 0; mt < 2; mt++)
                af[mt] = *(const bf16x8*)&hB[mt * 16 + lr][kt * 32 + (quad << 3)];
#pragma unroll
            for (int nt = 0; nt < 4; nt++) {
                bf16x8 bfr = Bp[(kt * 16 + (wv * 4 + nt)) * 64 + ln];
#pragma unroll
                for (int mt = 0; mt < 2; mt++)
                    acc[mt][nt] = __builtin_amdgcn_mfma_f32_16x16x32_bf16(af[mt], bfr, acc[mt][nt], 0, 0, 0);
            }
        }
#pragma unroll
        for (int nt = 0; nt < 4; nt++) {
            int d = wv * 64 + nt * 16 + lr;
            float bias = W[W_E2B + d];
#pragma unroll
            for (int mt = 0; mt < 2; mt++)
#pragma unroll
                for (int reg = 0; reg < 4; reg++) {
                    int m = mt * 16 + quad * 4 + reg;
                    float v = acc[mt][nt][reg] + bias;
                    v = v > 0.f ? v : 0.01f * v;
                    aeB[m][d] = f2bbits(v);
                    aews[(r0 + m) * 256 + d] = v;
                }
        }
    }
    __syncthreads();
    {
        const bf16x8* Bs = (const bf16x8*)(W + W_S1P);
        f32x4 sac[2][4];
#pragma unroll
        for (int mt = 0; mt < 2; mt++)
#pragma unroll
            for (int nt = 0; nt < 4; nt++) sac[mt][nt] = (f32x4){0.f, 0.f, 0.f, 0.f};
#pragma unroll
        for (int kt = 0; kt < 8; kt++) {
            bf16x8 af[2];
#pragma unroll
            for (int mt = 0; mt < 2; mt++)
                af[mt] = *(const bf16x8*)&aeB[mt * 16 + lr][kt * 32 + (quad << 3)];
#pragma unroll
            for (int nt = 0; nt < 4; nt++) {
                bf16x8 bs = Bs[(kt * 16 + (wv * 4 + nt)) * 64 + ln];
#pragma unroll
                for (int mt = 0; mt < 2; mt++)
                    sac[mt][nt] = __builtin_amdgcn_mfma_f32_16x16x32_bf16(af[mt], bs, sac[mt][nt], 0, 0, 0);
            }
        }
#pragma unroll
        for (int nt = 0; nt < 4; nt++) {
            int d = wv * 64 + nt * 16 + lr;
            float bias = W[W_H1B + d];
#pragma unroll
            for (int mt = 0; mt < 2; mt++)
#pragma unroll
                for (int reg = 0; reg < 4; reg++) {
                    int m = mt * 16 + quad * 4 + reg;
                    s1ws[(r0 + m) * 256 + d] = sac[mt][nt][reg] + bias;
                }
        }
        // qk = ae @ M (256x16, 10 real cols); waves 0,1 each take one m-tile
        if (wv < 2) {
            const bf16x8* Bm = (const bf16x8*)(W + W_QKM);
            f32x4 qk = (f32x4){0.f, 0.f, 0.f, 0.f};
#pragma unroll
            for (int kt = 0; kt < 8; kt++) {
                bf16x8 af = *(const bf16x8*)&aeB[wv * 16 + lr][kt * 32 + (quad << 3)];
                qk = __builtin_amdgcn_mfma_f32_16x16x32_bf16(af, Bm[kt * 64 + ln], qk, 0, 0, 0);
            }
            if (lr < 10) {
#pragma unroll
                for (int reg = 0; reg < 4; reg++) {
                    int m = wv * 16 + quad * 4 + reg;
                    qkws[(r0 + m) * 10 + lr] = qk[reg];
                }
            }
        }
    }
}

// ---------------- K2: edge features (7) + goal polar (3) ----------------
__global__ void k_edges(const void* emb, const int* flagp, float* sews, void* out) {
    int flag = flagp[0];
    int idx = blockIdx.x * 256 + threadIdx.x;
    if (idx >= R_TOT * NJ) return;
    int r = idx / NJ, jp = idx - r * NJ;
    int b = r >> 5, i = r & 31;
    int j = jp + (jp >= i ? 1 : 0);
    int ei = r * 11, ej = (b * 32 + j) * 11;
    float pix = ldin(emb, ei + 0, flag), piy = ldin(emb, ei + 1, flag);
    float hix = ldin(emb, ei + 2, flag), hiy = ldin(emb, ei + 3, flag);
    float pjx = ldin(emb, ej + 0, flag), pjy = ldin(emb, ej + 1, flag);
    float hjx = ldin(emb, ej + 2, flag), hjy = ldin(emb, ej + 3, flag);
    float ajx = ldin(emb, ej + 7, flag), ajy = ldin(emb, ej + 8, flag);
    float gjx = ldin(emb, ej + 9, flag), gjy = ldin(emb, ej + 10, flag);
    float dx = pjx - pix, dy = pjy - piy;
    float dist = sqrtf(dx * dx + dy * dy);
    float hai = atan2f(hiy, hix);
    float ang = atan2f(dy, dx) - hai;
    float gx = gjx - pix, gy = gjy - piy;
    float gdist = sqrtf(gx * gx + gy * gy);
    float gang = atan2f(gy, gx) - hai;
    float* o = sews + idx * 10;
    o[0] = dist * (1.f / 12.f);
    o[1] = cosf(ang); o[2] = sinf(ang);
    o[3] = hjx; o[4] = hjy; o[5] = ajx; o[6] = ajy;
    o[7] = gdist; o[8] = cosf(gang); o[9] = sinf(gang);
    stout(out, OUT2 + idx, dist, flag);
}

// ---------------- K3: hard MLP via MFMA + gumbel ----------------
__global__ __launch_bounds__(256) void k_hard(const float* s1ws, const float* sews, const float* W,
                                              const void* gum, const int* flagp,
                                              float* hwws, void* out) {
    int flag = flagp[0];
    int r = blockIdx.x;
    __shared__ unsigned short a1[32][264];
    __shared__ float edg[32][8];
    __shared__ float pj0[4][32];
    __shared__ float pj1[4][32];
    int tid = threadIdx.x;
    {
        int j = tid >> 3, t = tid & 7;
        float v = 0.f;
        if (j < NJ && t < 7) v = sews[(r * NJ + j) * 10 + t];
        edg[j][t] = v;
    }
    __syncthreads();
    float w1e[7];
#pragma unroll
    for (int t = 0; t < 7; t++) w1e[t] = W[W_H1W + tid * 263 + 256 + t];
    float s1c = s1ws[r * 256 + tid];
    for (int j = 0; j < 32; j++) {
        float v = s1c;
#pragma unroll
        for (int t = 0; t < 7; t++) v += w1e[t] * edg[j][t];
        a1[j][tid] = f2bbits(fmaxf(v, 0.f));
    }
    __syncthreads();
    int wv = tid >> 6, ln = tid & 63;
    int lr = ln & 15, quad = ln >> 4;
    const bf16x8* Bp = (const bf16x8*)(W + W_H2WT);
    f32x4 acc[2][4];
#pragma unroll
    for (int mt = 0; mt < 2; mt++)
#pragma unroll
        for (int nt = 0; nt < 4; nt++) acc[mt][nt] = (f32x4){0.f, 0.f, 0.f, 0.f};
#pragma unroll
    for (int kt = 0; kt < 8; kt++) {
        bf16x8 af[2];
#pragma unroll
        for (int mt = 0; mt < 2; mt++)
            af[mt] = *(const bf16x8*)&a1[mt * 16 + lr][kt * 32 + (quad << 3)];
#pragma unroll
        for (int nt = 0; nt < 4; nt++) {
            bf16x8 bfr = Bp[(kt * 16 + (wv * 4 + nt)) * 64 + ln];
#pragma unroll
            for (int mt = 0; mt < 2; mt++)
                acc[mt][nt] = __builtin_amdgcn_mfma_f32_16x16x32_bf16(af[mt], bfr, acc[mt][nt], 0, 0, 0);
        }
    }
    float he0v[4], he1v[4], b2v[4];
#pragma unroll
    for (int nt = 0; nt < 4; nt++) {
        int d = wv * 64 + nt * 16 + lr;
        he0v[nt] = W[W_HEW + d];
        he1v[nt] = W[W_HEW + 256 + d];
        b2v[nt]  = W[W_H2B + d];
    }
    float cb0 = 0.f, cb1 = 0.f;
#pragma unroll
    for (int nt = 0; nt < 4; nt++) { cb0 += he0v[nt] * b2v[nt]; cb1 += he1v[nt] * b2v[nt]; }
#pragma unroll
    for (int mt = 0; mt < 2; mt++) {
#pragma unroll
        for (int reg = 0; reg < 4; reg++) {
            float p0 = cb0, p1 = cb1;
#pragma unroll
            for (int nt = 0; nt < 4; nt++) {
                float v = acc[mt][nt][reg];
                p0 += he0v[nt] * v;
                p1 += he1v[nt] * v;
            }
#pragma unroll
            for (int s = 1; s <= 8; s <<= 1) {
                p0 += __shfl_xor(p0, s, 64);
                p1 += __shfl_xor(p1, s, 64);
            }
            if (lr == 0) {
                int j = mt * 16 + quad * 4 + reg;
                pj0[wv][j] = p0;
                pj1[wv][j] = p1;
            }
        }
    }
    __syncthreads();
    if (tid < NJ) {
        int j = tid;
        float p0 = pj0[0][j] + pj0[1][j] + pj0[2][j] + pj0[3][j];
        float p1 = pj1[0][j] + pj1[1][j] + pj1[2][j] + pj1[3][j];
        float l0 = p0 + W[W_HEB + 0], l1 = p1 + W[W_HEB + 1];
        float u0 = ldin(gum, (r * NJ + j) * 2 + 0, flag);
        float u1 = ldin(gum, (r * NJ + j) * 2 + 1, flag);
        float g0 = -logf(-logf(u0 + 1e-10f) + 1e-10f);
        float g1 = -logf(-logf(u1 + 1e-10f) + 1e-10f);
        float dl = ((l1 + g1) - (l0 + g0)) * 2.0f;  // / tau (=0.5)
        float hwv = 1.f / (1.f + expf(-dl));
        stout(out, OUT1 + r * NJ + j, l1, flag);
        stout(out, OUT4 + r * NJ + j, hwv, flag);
        hwws[r * NJ + j] = hwv;
    }
}

// ---------------- K4: attention via qk-fold + softmax + V+x + entropy ----------------
__global__ __launch_bounds__(256) void k_attn(const float* qkws, const float* sews, const float* hwws,
                                              const float* W, const int* flagp,
                                              float* xws, float* entws, void* out) {
    int flag = flagp[0];
    int r = blockIdx.x;
    __shared__ float seL[NJ][10];
    __shared__ float cL[32];
    __shared__ float qkL[10];
    int tid = threadIdx.x;
    for (int idx = tid; idx < NJ * 10; idx += 256) ((float*)seL)[idx] = sews[r * NJ * 10 + idx];
    if (tid < 10) qkL[tid] = qkws[r * 10 + tid];
    __syncthreads();
    int wv = tid >> 6, ln = tid & 63;
    if (wv == 0) {
        float sc = -1e30f;
        if (ln < NJ) {
            float p = 0.f;
#pragma unroll
            for (int t = 0; t < 10; t++) p += qkL[t] * seL[ln][t];
            sc = p * (1.f / 16.f);
        }
        float m = sc;
#pragma unroll
        for (int s = 32; s >= 1; s >>= 1) m = fmaxf(m, __shfl_xor(m, s, 64));
        float e = (ln < NJ) ? expf(sc - m) : 0.f;
        float sum = e;
#pragma unroll
        for (int s = 32; s >= 1; s >>= 1) sum += __shfl_xor(sum, s, 64);
        float sw = e / sum;
        float hv = (ln < NJ) ? hwws[r * NJ + ln] : 0.f;
        float cmb = sw * hv;
        if (ln < NJ) {
            cL[ln] = cmb;
            stout(out, OUT5 + r * NJ + ln, cmb, flag);
        }
        float csum = cmb;
#pragma unroll
        for (int s = 32; s >= 1; s >>= 1) csum += __shfl_xor(csum, s, 64);
        float cwn = cmb / (csum + 1e-6f);
        float et = (ln < NJ) ? -cwn * logf(cwn + 1e-6f) : 0.f;
#pragma unroll
        for (int s = 32; s >= 1; s >>= 1) et += __shfl_xor(et, s, 64);
        if (ln == 0) entws[r] = et;
    }
    __syncthreads();
    float vwr[10];
#pragma unroll
    for (int t = 0; t < 10; t++) vwr[t] = W[W_VW + tid * 10 + t];
    float vbv = W[W_VB + tid];
    float x = 0.f;
    for (int j = 0; j < NJ; j++) {
        float v = vbv;
#pragma unroll
        for (int t = 0; t < 10; t++) v += vwr[t] * seL[j][t];
        v = fmaxf(v, 0.f);
        x += v * cL[j];
    }
    xws[r * 256 + tid] = x;
}

// ---------------- K5: decoder via MFMA ----------------
__global__ __launch_bounds__(256) void k_dec(const float* aews, const float* xws, const float* W,
                                             const int* flagp, void* out) {
    int flag = flagp[0];
    int r0 = (blockIdx.x >> 2) * 32;
    int nq = blockIdx.x & 3;
    __shared__ unsigned short finB[32][520];
    int tid = threadIdx.x;
    for (int idx = tid; idx < 32 * 512; idx += 256) {
        int s = idx >> 9, c = idx & 511;
        float v = (c < 256) ? aews[(r0 + s) * 256 + c] : xws[(r0 + s) * 256 + (c - 256)];
        finB[s][c] = f2bbits(v);
    }
    __syncthreads();
    int wv = tid >> 6, ln = tid & 63;
    int lr = ln & 15, quad = ln >> 4;
    const bf16x8* Bp = (const bf16x8*)(W + W_DECWT);
    f32x4 acc[2][2];
#pragma unroll
    for (int mt = 0; mt < 2; mt++)
#pragma unroll
        for (int nt = 0; nt < 2; nt++) acc[mt][nt] = (f32x4){0.f, 0.f, 0.f, 0.f};
#pragma unroll
    for (int kt = 0; kt < 16; kt++) {
        bf16x8 af[2];
#pragma unroll
        for (int mt = 0; mt < 2; mt++)
            af[mt] = *(const bf16x8*)&finB[mt * 16 + lr][kt * 32 + (quad << 3)];
#pragma unroll
        for (int nt = 0; nt < 2; nt++) {
            int gnt = nq * 8 + wv * 2 + nt;
            bf16x8 bfr = Bp[(kt * 32 + gnt) * 64 + ln];
#pragma unroll
            for (int mt = 0; mt < 2; mt++)
                acc[mt][nt] = __builtin_amdgcn_mfma_f32_16x16x32_bf16(af[mt], bfr, acc[mt][nt], 0, 0, 0);
        }
    }
#pragma unroll
    for (int nt = 0; nt < 2; nt++) {
        int d = (nq * 8 + wv * 2 + nt) * 16 + lr;
        float bias = W[W_DECB + d];
#pragma unroll
        for (int mt = 0; mt < 2; mt++)
#pragma unroll
            for (int reg = 0; reg < 4; reg++) {
                int m = mt * 16 + quad * 4 + reg;
                stout(out, OUT0 + (r0 + m) * 512 + d, acc[mt][nt][reg] + bias, flag);
            }
    }
}

// ---------------- K6: entropy mean ----------------
__global__ void k_ent(const float* entws, const int* flagp, void* out) {
    __shared__ float red[4];
    int tid = threadIdx.x;
    float s = 0.f;
    for (int i = tid; i < R_TOT; i += 256) s += entws[i];
#pragma unroll
    for (int m = 32; m >= 1; m >>= 1) s += __shfl_xor(s, m, 64);
    if ((tid & 63) == 0) red[tid >> 6] = s;
    __syncthreads();
    if (tid == 0) {
        float t = red[0] + red[1] + red[2] + red[3];
        stout(out, OUT3, t / (float)R_TOT, flagp[0]);
    }
}

// ---------------- launch ----------------
extern "C" void kernel_launch(void* const* d_in, const int* in_sizes, int n_in,
                              void* d_out, int out_size, void* d_ws, size_t ws_size,
                              hipStream_t stream) {
    const void* emb  = d_in[0];
    const void* gum  = d_in[1];
    const void* e1w  = d_in[2];
    const void* e1b  = d_in[3];
    const void* e2w  = d_in[4];
    const void* e2b  = d_in[5];
    const void* h1w  = d_in[6];
    const void* h1b  = d_in[7];
    const void* h2w  = d_in[8];
    const void* h2b  = d_in[9];
    const void* hew  = d_in[10];
    const void* heb  = d_in[11];
    const void* qw   = d_in[12];
    const void* kw   = d_in[13];
    const void* vw   = d_in[14];
    const void* vb   = d_in[15];
    const void* decw = d_in[16];
    const void* decb = d_in[17];

    float* wsf = (float*)d_ws;
    float* aews = wsf + OFF_AE;
    float* qkws = wsf + OFF_QK;
    float* s1ws = wsf + OFF_S1;
    float* sews = wsf + OFF_SE;
    float* hwws = wsf + OFF_HW;
    float* entw = wsf + OFF_ENT;
    float* xws  = wsf + OFF_X;
    float* W    = wsf + OFF_W;
    int* flagp  = (int*)(wsf + OFF_FLAG);

    hipLaunchKernelGGL(k_detect, dim3(1), dim3(64), 0, stream, emb, flagp);
    hipLaunchKernelGGL(k_conv, dim3(2048), dim3(256), 0, stream,
                       e1w, e1b, e2w, e2b, h1w, h1b, h2w, h2b, hew, heb,
                       qw, kw, vw, vb, decw, decb, W, flagp);
    hipLaunchKernelGGL(k_qkm, dim3(16), dim3(256), 0, stream, qw, kw, W, flagp);
    hipLaunchKernelGGL(k_embed, dim3(128), dim3(256), 0, stream, emb, W, flagp, aews, qkws, s1ws);
    hipLaunchKernelGGL(k_edges, dim3(496), dim3(256), 0, stream, emb, flagp, sews, d_out);
    hipLaunchKernelGGL(k_hard, dim3(4096), dim3(256), 0, stream,
                       s1ws, sews, W, gum, flagp, hwws, d_out);
    hipLaunchKernelGGL(k_attn, dim3(4096), dim3(256), 0, stream,
                       qkws, sews, hwws, W, flagp, xws, entw, d_out);
    hipLaunchKernelGGL(k_dec, dim3(512), dim3(256), 0, stream, aews, xws, W, flagp, d_out);
    hipLaunchKernelGGL(k_ent, dim3(1), dim3(256), 0, stream, entw, flagp, d_out);
}